// Round 3
// baseline (1200.241 us; speedup 1.0000x reference)
//
#include <hip/hip_runtime.h>
#include <hip/hip_bf16.h>
#include <math.h>

#define N_NODES 50000
#define NE      800000
#define ETOT    (NE + N_NODES)   // edges + self loops = 850000
#define F       128              // F_in == H*C
#define NHEAD   4
#define NEG     0.2f

#define SCAN_B 256
#define NBLK   ((N_NODES + SCAN_B - 1) / SCAN_B)   // 196

// ---------------- CSR build ----------------

__global__ void k_zero(int* __restrict__ p, int n) {
    int i = blockIdx.x * blockDim.x + threadIdx.x;
    if (i < n) p[i] = 0;
}

__global__ void k_deg(const int* __restrict__ ei, int* __restrict__ deg) {
    int i = blockIdx.x * blockDim.x + threadIdx.x;
    if (i < ETOT) {
        int d = (i < NE) ? ei[NE + i] : (i - NE);
        atomicAdd(&deg[d], 1);
    }
}

__global__ void k_scan1(const int* __restrict__ deg, int* __restrict__ bsum) {
    __shared__ int sm[SCAN_B];
    int i = blockIdx.x * SCAN_B + threadIdx.x;
    sm[threadIdx.x] = (i < N_NODES) ? deg[i] : 0;
    __syncthreads();
    for (int s = SCAN_B / 2; s > 0; s >>= 1) {
        if (threadIdx.x < s) sm[threadIdx.x] += sm[threadIdx.x + s];
        __syncthreads();
    }
    if (threadIdx.x == 0) bsum[blockIdx.x] = sm[0];
}

__global__ void k_scan2(int* __restrict__ bsum) {
    __shared__ int sm[SCAN_B];
    int t = threadIdx.x;
    int v = (t < NBLK) ? bsum[t] : 0;
    sm[t] = v; __syncthreads();
    for (int s = 1; s < SCAN_B; s <<= 1) {
        int a = (t >= s) ? sm[t - s] : 0;
        __syncthreads();
        sm[t] += a;
        __syncthreads();
    }
    if (t < NBLK) bsum[t] = sm[t] - v;  // exclusive
}

__global__ void k_scan3(const int* __restrict__ deg, const int* __restrict__ bsum,
                        int* __restrict__ rowptr, int* __restrict__ cursor) {
    __shared__ int sm[SCAN_B];
    int t = threadIdx.x;
    int i = blockIdx.x * SCAN_B + t;
    int v = (i < N_NODES) ? deg[i] : 0;
    sm[t] = v; __syncthreads();
    for (int s = 1; s < SCAN_B; s <<= 1) {
        int a = (t >= s) ? sm[t - s] : 0;
        __syncthreads();
        sm[t] += a;
        __syncthreads();
    }
    int excl = sm[t] - v + bsum[blockIdx.x];
    if (i < N_NODES) { rowptr[i] = excl; cursor[i] = excl; }
    if (i == N_NODES - 1) rowptr[N_NODES] = excl + v;
}

__global__ void k_fill(const int* __restrict__ ei, int* __restrict__ cursor,
                       int* __restrict__ col) {
    int i = blockIdx.x * blockDim.x + threadIdx.x;
    if (i < ETOT) {
        int s, d;
        if (i < NE) { s = ei[i]; d = ei[NE + i]; }
        else        { s = i - NE; d = s; }
        int pos = atomicAdd(&cursor[d], 1);
        col[pos] = s;
    }
}

// ---------------- GEMM + fused alpha: h = X @ W^T, asrc/adst per node/head ----
// 64 nodes/block, 256 threads, each thread 4 nodes x 8 j (j = tx + jj*16).
// launch_bounds(256,3): cap VGPRs at ~170 so the 4x8 acc + fragments never spill.

#define GM 64
#define KT 32
#define LPAD 36

__global__ __launch_bounds__(256, 3) void k_gemm(const float* __restrict__ X,
                                                 const float* __restrict__ W,
                                                 const float* __restrict__ a_s,
                                                 const float* __restrict__ a_d,
                                                 float* __restrict__ hout,
                                                 float* __restrict__ asrc,
                                                 float* __restrict__ adst) {
    __shared__ float Xs[GM * LPAD];
    __shared__ float Wsh[F * LPAD];
    int tid = threadIdx.x;
    int tx = tid & 15;    // j = tx + jj*16
    int ty = tid >> 4;    // nodes ty*4 .. ty*4+3
    int bm = blockIdx.x * GM;

    float acc[4][8];
#pragma unroll
    for (int i = 0; i < 4; i++)
#pragma unroll
        for (int j = 0; j < 8; j++) acc[i][j] = 0.f;

    for (int k0 = 0; k0 < F; k0 += KT) {
        // stage X tile: 64x32 floats = 512 float4, 2 per thread
#pragma unroll
        for (int u = 0; u < 2; u++) {
            int f4 = tid + 256 * u;
            int r = f4 >> 3, c4 = f4 & 7;
            int gr = bm + r;
            float4 v = make_float4(0.f, 0.f, 0.f, 0.f);
            if (gr < N_NODES) v = *(const float4*)&X[(size_t)gr * F + k0 + c4 * 4];
            *(float4*)&Xs[r * LPAD + c4 * 4] = v;
        }
        // stage W tile: 128x32 floats = 1024 float4, 4 per thread
#pragma unroll
        for (int u = 0; u < 4; u++) {
            int f4 = tid + 256 * u;
            int r = f4 >> 3, c4 = f4 & 7;
            *(float4*)&Wsh[r * LPAD + c4 * 4] = *(const float4*)&W[r * F + k0 + c4 * 4];
        }
        __syncthreads();

#pragma unroll
        for (int kk = 0; kk < KT; kk += 4) {
            float4 xv[4], wv[8];
#pragma unroll
            for (int i = 0; i < 4; i++) xv[i] = *(float4*)&Xs[(ty * 4 + i) * LPAD + kk];
#pragma unroll
            for (int j = 0; j < 8; j++) wv[j] = *(float4*)&Wsh[(tx + j * 16) * LPAD + kk];
#pragma unroll
            for (int i = 0; i < 4; i++)
#pragma unroll
                for (int j = 0; j < 8; j++)
                    acc[i][j] += xv[i].x * wv[j].x + xv[i].y * wv[j].y
                               + xv[i].z * wv[j].z + xv[i].w * wv[j].w;
        }
        __syncthreads();
    }

    // epilogue: store h + fused per-node attention logits
    float as_v[8], ad_v[8];
#pragma unroll
    for (int jj = 0; jj < 8; jj++) {
        as_v[jj] = a_s[tx + jj * 16];
        ad_v[jj] = a_d[tx + jj * 16];
    }
#pragma unroll
    for (int i = 0; i < 4; i++) {
        int n = bm + ty * 4 + i;
        bool ok = (n < N_NODES);
        if (ok) {
#pragma unroll
            for (int jj = 0; jj < 8; jj++) hout[(size_t)n * F + tx + jj * 16] = acc[i][jj];
        }
        float ps[4], pd[4];
#pragma unroll
        for (int hh = 0; hh < 4; hh++) {
            ps[hh] = acc[i][2 * hh] * as_v[2 * hh] + acc[i][2 * hh + 1] * as_v[2 * hh + 1];
            pd[hh] = acc[i][2 * hh] * ad_v[2 * hh] + acc[i][2 * hh + 1] * ad_v[2 * hh + 1];
        }
#pragma unroll
        for (int s = 1; s < 16; s <<= 1) {
#pragma unroll
            for (int hh = 0; hh < 4; hh++) {
                ps[hh] += __shfl_xor(ps[hh], s);
                pd[hh] += __shfl_xor(pd[hh], s);
            }
        }
        if (ok && tx == 0) {
            *(float4*)&asrc[n * 4] = make_float4(ps[0], ps[1], ps[2], ps[3]);
            *(float4*)&adst[n * 4] = make_float4(pd[0], pd[1], pd[2], pd[3]);
        }
    }
}

// ---------------- fused softmax + aggregate, one wave per dst node ----------------

__device__ __forceinline__ float selh(float4 v, int h) {
    float r = v.x;
    r = (h == 1) ? v.y : r;
    r = (h == 2) ? v.z : r;
    r = (h == 3) ? v.w : r;
    return r;
}

__global__ __launch_bounds__(256) void k_aggr(const float* __restrict__ h,
                                              const float* __restrict__ asrc,
                                              const float* __restrict__ adst,
                                              const int* __restrict__ rowptr,
                                              const int* __restrict__ col,
                                              const float* __restrict__ bias,
                                              float* __restrict__ xout) {
    __shared__ int   scol[4][64];
    __shared__ float sw[4][64 * 4];
    int wave = threadIdx.x >> 6;
    int lane = threadIdx.x & 63;
    int n = blockIdx.x * 4 + wave;
    if (n >= N_NODES) return;
    int head = lane >> 4;                // lane owns channels 2*lane, 2*lane+1
    int beg = rowptr[n], end = rowptr[n + 1];
    float4 ad4 = *(const float4*)&adst[n * 4];

    float4 m4 = make_float4(-1e30f, -1e30f, -1e30f, -1e30f);
    float4 s4 = make_float4(0.f, 0.f, 0.f, 0.f);
    float accx = 0.f, accy = 0.f;

    for (int base = beg; base < end; base += 64) {
        int cnt = end - base; if (cnt > 64) cnt = 64;
        int sidx = 0;
        float4 e4 = make_float4(-1e30f, -1e30f, -1e30f, -1e30f);
        if (lane < cnt) {
            sidx = col[base + lane];
            float4 av = *(const float4*)&asrc[sidx * 4];
            float ex = av.x + ad4.x, ey = av.y + ad4.y,
                  ez = av.z + ad4.z, ew = av.w + ad4.w;
            e4.x = (ex > 0.f) ? ex : NEG * ex;
            e4.y = (ey > 0.f) ? ey : NEG * ey;
            e4.z = (ez > 0.f) ? ez : NEG * ez;
            e4.w = (ew > 0.f) ? ew : NEG * ew;
        }
        scol[wave][lane] = sidx;
        float4 M4 = e4;
#pragma unroll
        for (int s = 1; s < 64; s <<= 1) {
            M4.x = fmaxf(M4.x, __shfl_xor(M4.x, s));
            M4.y = fmaxf(M4.y, __shfl_xor(M4.y, s));
            M4.z = fmaxf(M4.z, __shfl_xor(M4.z, s));
            M4.w = fmaxf(M4.w, __shfl_xor(M4.w, s));
        }
        float4 nm;
        nm.x = fmaxf(m4.x, M4.x); nm.y = fmaxf(m4.y, M4.y);
        nm.z = fmaxf(m4.z, M4.z); nm.w = fmaxf(m4.w, M4.w);
        float4 sc;
        sc.x = __expf(m4.x - nm.x); sc.y = __expf(m4.y - nm.y);
        sc.z = __expf(m4.z - nm.z); sc.w = __expf(m4.w - nm.w);
        s4.x *= sc.x; s4.y *= sc.y; s4.z *= sc.z; s4.w *= sc.w;
        float rs = selh(sc, head);
        accx *= rs; accy *= rs;
        float4 w4;
        w4.x = (lane < cnt) ? __expf(e4.x - nm.x) : 0.f;
        w4.y = (lane < cnt) ? __expf(e4.y - nm.y) : 0.f;
        w4.z = (lane < cnt) ? __expf(e4.z - nm.z) : 0.f;
        w4.w = (lane < cnt) ? __expf(e4.w - nm.w) : 0.f;
        *(float4*)&sw[wave][lane * 4] = w4;
        float4 S4 = w4;
#pragma unroll
        for (int s = 1; s < 64; s <<= 1) {
            S4.x += __shfl_xor(S4.x, s);
            S4.y += __shfl_xor(S4.y, s);
            S4.z += __shfl_xor(S4.z, s);
            S4.w += __shfl_xor(S4.w, s);
        }
        s4.x += S4.x; s4.y += S4.y; s4.z += S4.z; s4.w += S4.w;
        m4 = nm;
#pragma unroll 4
        for (int p = 0; p < cnt; p++) {
            int s = scol[wave][p];
            float wgt = sw[wave][p * 4 + head];
            float2 hv = *(const float2*)&h[(size_t)s * F + lane * 2];
            accx = fmaf(wgt, hv.x, accx);
            accy = fmaf(wgt, hv.y, accy);
        }
    }

    float ssum = selh(s4, head);
    float inv = 1.f / (ssum + 1e-16f);
    float2 b2 = *(const float2*)&bias[lane * 2];
    float ox = fmaxf(fmaf(accx, inv, b2.x), 0.f);
    float oy = fmaxf(fmaf(accy, inv, b2.y), 0.f);
    *(float2*)&xout[(size_t)n * F + lane * 2] = make_float2(ox, oy);
}

// ---------------- final linear 128 -> 32, LDS-tiled ----------------
// 64 nodes/block. Wf staged TRANSPOSED (stride 33 -> bank (k+o)%32, conflict-
// free); X tile staged coalesced (stride 132). Thread (o=tid&31, g=tid>>5)
// computes 8 nodes x 1 output from LDS broadcasts.

__global__ __launch_bounds__(256) void k_fc(const float* __restrict__ X,
                                            const float* __restrict__ Wf,
                                            const float* __restrict__ bf,
                                            float* __restrict__ out) {
    __shared__ float Xs[64 * 132];    // 33.8 KB
    __shared__ float Wt[128 * 33];    // 16.9 KB, Wt[k*33+o] = Wf[o*128+k]
    int tid = threadIdx.x;
    int bm = blockIdx.x * 64;

#pragma unroll
    for (int u = 0; u < 16; u++) {
        int idx = tid + 256 * u;          // 0..4095
        int o = idx >> 7, k = idx & 127;
        Wt[k * 33 + o] = Wf[idx];
    }
#pragma unroll
    for (int u = 0; u < 8; u++) {
        int f4 = tid + 256 * u;           // 0..2047
        int r = f4 >> 5, c4 = f4 & 31;
        int n = bm + r;
        float4 v = make_float4(0.f, 0.f, 0.f, 0.f);
        if (n < N_NODES) v = *(const float4*)&X[(size_t)n * F + c4 * 4];
        *(float4*)&Xs[r * 132 + c4 * 4] = v;
    }
    __syncthreads();

    int o = tid & 31, g = tid >> 5;       // 8 groups x 8 nodes
    float acc[8];
#pragma unroll
    for (int i = 0; i < 8; i++) acc[i] = 0.f;

    for (int k = 0; k < 128; k += 4) {
        float w0 = Wt[(k + 0) * 33 + o];
        float w1 = Wt[(k + 1) * 33 + o];
        float w2 = Wt[(k + 2) * 33 + o];
        float w3 = Wt[(k + 3) * 33 + o];
#pragma unroll
        for (int i = 0; i < 8; i++) {
            float4 xv = *(float4*)&Xs[(g * 8 + i) * 132 + k];
            acc[i] += xv.x * w0 + xv.y * w1 + xv.z * w2 + xv.w * w3;
        }
    }
    float bo = bf[o];
#pragma unroll
    for (int i = 0; i < 8; i++) {
        int n = bm + g * 8 + i;
        if (n < N_NODES) out[n * 32 + o] = acc[i] + bo;
    }
}

// ---------------- launch ----------------

extern "C" void kernel_launch(void* const* d_in, const int* in_sizes, int n_in,
                              void* d_out, int out_size, void* d_ws, size_t ws_size,
                              hipStream_t stream) {
    const float* x      = (const float*)d_in[0];   // [N,128]
    const float* Ws     = (const float*)d_in[1];   // [3,128,128]
    const float* a_src  = (const float*)d_in[2];   // [3,4,32]
    const float* a_dst  = (const float*)d_in[3];   // [3,4,32]
    const float* cbias  = (const float*)d_in[4];   // [3,128]
    const float* Wf     = (const float*)d_in[5];   // [32,128]
    const float* bf     = (const float*)d_in[6];   // [32]
    const int*   ei     = (const int*)d_in[7];     // [2,800000]
    float* out = (float*)d_out;

    char* p = (char*)d_ws;
    auto carve = [&](size_t bytes) {
        char* r = p;
        p += (bytes + 255) & ~(size_t)255;
        return r;
    };
    float* xA   = (float*)carve((size_t)N_NODES * F * 4);
    float* xB   = (float*)carve((size_t)N_NODES * F * 4);
    float* hbuf = (float*)carve((size_t)N_NODES * F * 4);
    float* asrc = (float*)carve((size_t)N_NODES * NHEAD * 4);
    float* adst = (float*)carve((size_t)N_NODES * NHEAD * 4);
    int* deg    = (int*)carve((size_t)N_NODES * 4);
    int* rowptr = (int*)carve((size_t)(N_NODES + 1) * 4);
    int* cursor = (int*)carve((size_t)N_NODES * 4);
    int* bsum   = (int*)carve((size_t)SCAN_B * 4);
    int* col    = (int*)carve((size_t)ETOT * 4);

    // ---- CSR build (dst-sorted adjacency) ----
    k_zero<<<(N_NODES + 255) / 256, 256, 0, stream>>>(deg, N_NODES);
    k_deg<<<(ETOT + 255) / 256, 256, 0, stream>>>(ei, deg);
    k_scan1<<<NBLK, SCAN_B, 0, stream>>>(deg, bsum);
    k_scan2<<<1, SCAN_B, 0, stream>>>(bsum);
    k_scan3<<<NBLK, SCAN_B, 0, stream>>>(deg, bsum, rowptr, cursor);
    k_fill<<<(ETOT + 255) / 256, 256, 0, stream>>>(ei, cursor, col);

    // ---- 3 GAT layers ----
    const float* xin = x;
    float* bufs[2] = {xA, xB};
    for (int l = 0; l < 3; l++) {
        k_gemm<<<(N_NODES + GM - 1) / GM, 256, 0, stream>>>(
            xin, Ws + (size_t)l * F * F, a_src + l * F, a_dst + l * F,
            hbuf, asrc, adst);
        k_aggr<<<(N_NODES + 3) / 4, 256, 0, stream>>>(hbuf, asrc, adst, rowptr, col,
                                                      cbias + l * F, bufs[l & 1]);
        xin = bufs[l & 1];
    }

    // ---- final linear ----
    k_fc<<<(N_NODES * 32 + 255) / 256, 256, 0, stream>>>(xin, Wf, bf, out);
}

// Round 4
// 652.165 us; speedup vs baseline: 1.8404x; 1.8404x over previous
//
#include <hip/hip_runtime.h>
#include <hip/hip_bf16.h>
#include <math.h>

#define N_NODES 50000
#define NE      800000
#define ETOT    (NE + N_NODES)   // edges + self loops = 850000
#define F       128              // F_in == H*C
#define NHEAD   4
#define NEG     0.2f

#define SCAN_B 256
#define NBLK   ((N_NODES + SCAN_B - 1) / SCAN_B)   // 196

// ---------------- CSR build ----------------

__global__ void k_zero(int* __restrict__ p, int n) {
    int i = blockIdx.x * blockDim.x + threadIdx.x;
    if (i < n) p[i] = 0;
}

__global__ void k_deg(const int* __restrict__ ei, int* __restrict__ deg) {
    int i = blockIdx.x * blockDim.x + threadIdx.x;
    if (i < ETOT) {
        int d = (i < NE) ? ei[NE + i] : (i - NE);
        atomicAdd(&deg[d], 1);
    }
}

__global__ void k_scan1(const int* __restrict__ deg, int* __restrict__ bsum) {
    __shared__ int sm[SCAN_B];
    int i = blockIdx.x * SCAN_B + threadIdx.x;
    sm[threadIdx.x] = (i < N_NODES) ? deg[i] : 0;
    __syncthreads();
    for (int s = SCAN_B / 2; s > 0; s >>= 1) {
        if (threadIdx.x < s) sm[threadIdx.x] += sm[threadIdx.x + s];
        __syncthreads();
    }
    if (threadIdx.x == 0) bsum[blockIdx.x] = sm[0];
}

__global__ void k_scan2(int* __restrict__ bsum) {
    __shared__ int sm[SCAN_B];
    int t = threadIdx.x;
    int v = (t < NBLK) ? bsum[t] : 0;
    sm[t] = v; __syncthreads();
    for (int s = 1; s < SCAN_B; s <<= 1) {
        int a = (t >= s) ? sm[t - s] : 0;
        __syncthreads();
        sm[t] += a;
        __syncthreads();
    }
    if (t < NBLK) bsum[t] = sm[t] - v;  // exclusive
}

__global__ void k_scan3(const int* __restrict__ deg, const int* __restrict__ bsum,
                        int* __restrict__ rowptr, int* __restrict__ cursor) {
    __shared__ int sm[SCAN_B];
    int t = threadIdx.x;
    int i = blockIdx.x * SCAN_B + t;
    int v = (i < N_NODES) ? deg[i] : 0;
    sm[t] = v; __syncthreads();
    for (int s = 1; s < SCAN_B; s <<= 1) {
        int a = (t >= s) ? sm[t - s] : 0;
        __syncthreads();
        sm[t] += a;
        __syncthreads();
    }
    int excl = sm[t] - v + bsum[blockIdx.x];
    if (i < N_NODES) { rowptr[i] = excl; cursor[i] = excl; }
    if (i == N_NODES - 1) rowptr[N_NODES] = excl + v;
}

__global__ void k_fill(const int* __restrict__ ei, int* __restrict__ cursor,
                       int* __restrict__ col) {
    int i = blockIdx.x * blockDim.x + threadIdx.x;
    if (i < ETOT) {
        int s, d;
        if (i < NE) { s = ei[i]; d = ei[NE + i]; }
        else        { s = i - NE; d = s; }
        int pos = atomicAdd(&cursor[d], 1);
        col[pos] = s;
    }
}

// ---------------- GEMM + fused alpha: h = X @ W^T, asrc/adst per node/head ----
// 64 nodes/block, 256 threads, each thread 4 nodes x 8 j (j = tx + jj*16).
// NOTE: plain __launch_bounds__(256). The (256,3) variant made the allocator
// target ~84 VGPRs -> acc spilled to scratch in the inner loop -> 585 MB
// WRITE_SIZE and 277 us/dispatch (round-3 counters). Do not add a 2nd arg.

#define GM 64
#define KT 32
#define LPAD 36

__global__ __launch_bounds__(256) void k_gemm(const float* __restrict__ X,
                                              const float* __restrict__ W,
                                              const float* __restrict__ a_s,
                                              const float* __restrict__ a_d,
                                              float* __restrict__ hout,
                                              float* __restrict__ asrc,
                                              float* __restrict__ adst) {
    __shared__ float Xs[GM * LPAD];
    __shared__ float Wsh[F * LPAD];
    int tid = threadIdx.x;
    int tx = tid & 15;    // j = tx + jj*16
    int ty = tid >> 4;    // nodes ty*4 .. ty*4+3
    int bm = blockIdx.x * GM;

    float acc[4][8];
#pragma unroll
    for (int i = 0; i < 4; i++)
#pragma unroll
        for (int j = 0; j < 8; j++) acc[i][j] = 0.f;

    for (int k0 = 0; k0 < F; k0 += KT) {
        // stage X tile: 64x32 floats = 512 float4, 2 per thread
#pragma unroll
        for (int u = 0; u < 2; u++) {
            int f4 = tid + 256 * u;
            int r = f4 >> 3, c4 = f4 & 7;
            int gr = bm + r;
            float4 v = make_float4(0.f, 0.f, 0.f, 0.f);
            if (gr < N_NODES) v = *(const float4*)&X[(size_t)gr * F + k0 + c4 * 4];
            *(float4*)&Xs[r * LPAD + c4 * 4] = v;
        }
        // stage W tile: 128x32 floats = 1024 float4, 4 per thread
#pragma unroll
        for (int u = 0; u < 4; u++) {
            int f4 = tid + 256 * u;
            int r = f4 >> 3, c4 = f4 & 7;
            *(float4*)&Wsh[r * LPAD + c4 * 4] = *(const float4*)&W[r * F + k0 + c4 * 4];
        }
        __syncthreads();

#pragma unroll
        for (int kk = 0; kk < KT; kk += 4) {
            float4 xv[4], wv[8];
#pragma unroll
            for (int i = 0; i < 4; i++) xv[i] = *(float4*)&Xs[(ty * 4 + i) * LPAD + kk];
#pragma unroll
            for (int j = 0; j < 8; j++) wv[j] = *(float4*)&Wsh[(tx + j * 16) * LPAD + kk];
#pragma unroll
            for (int i = 0; i < 4; i++)
#pragma unroll
                for (int j = 0; j < 8; j++)
                    acc[i][j] += xv[i].x * wv[j].x + xv[i].y * wv[j].y
                               + xv[i].z * wv[j].z + xv[i].w * wv[j].w;
        }
        __syncthreads();
    }

    // epilogue: store h + fused per-node attention logits
    float as_v[8], ad_v[8];
#pragma unroll
    for (int jj = 0; jj < 8; jj++) {
        as_v[jj] = a_s[tx + jj * 16];
        ad_v[jj] = a_d[tx + jj * 16];
    }
#pragma unroll
    for (int i = 0; i < 4; i++) {
        int n = bm + ty * 4 + i;
        bool ok = (n < N_NODES);
        if (ok) {
#pragma unroll
            for (int jj = 0; jj < 8; jj++) hout[(size_t)n * F + tx + jj * 16] = acc[i][jj];
        }
        float ps[4], pd[4];
#pragma unroll
        for (int hh = 0; hh < 4; hh++) {
            ps[hh] = acc[i][2 * hh] * as_v[2 * hh] + acc[i][2 * hh + 1] * as_v[2 * hh + 1];
            pd[hh] = acc[i][2 * hh] * ad_v[2 * hh] + acc[i][2 * hh + 1] * ad_v[2 * hh + 1];
        }
#pragma unroll
        for (int s = 1; s < 16; s <<= 1) {
#pragma unroll
            for (int hh = 0; hh < 4; hh++) {
                ps[hh] += __shfl_xor(ps[hh], s);
                pd[hh] += __shfl_xor(pd[hh], s);
            }
        }
        if (ok && tx == 0) {
            *(float4*)&asrc[n * 4] = make_float4(ps[0], ps[1], ps[2], ps[3]);
            *(float4*)&adst[n * 4] = make_float4(pd[0], pd[1], pd[2], pd[3]);
        }
    }
}

// ---------------- fused softmax + aggregate, one wave per dst node ----------------

__device__ __forceinline__ float selh(float4 v, int h) {
    float r = v.x;
    r = (h == 1) ? v.y : r;
    r = (h == 2) ? v.z : r;
    r = (h == 3) ? v.w : r;
    return r;
}

__global__ __launch_bounds__(256) void k_aggr(const float* __restrict__ h,
                                              const float* __restrict__ asrc,
                                              const float* __restrict__ adst,
                                              const int* __restrict__ rowptr,
                                              const int* __restrict__ col,
                                              const float* __restrict__ bias,
                                              float* __restrict__ xout) {
    __shared__ int   scol[4][64];
    __shared__ float sw[4][64 * 4];
    int wave = threadIdx.x >> 6;
    int lane = threadIdx.x & 63;
    int n = blockIdx.x * 4 + wave;
    if (n >= N_NODES) return;
    int head = lane >> 4;                // lane owns channels 2*lane, 2*lane+1
    int beg = rowptr[n], end = rowptr[n + 1];
    float4 ad4 = *(const float4*)&adst[n * 4];

    float4 m4 = make_float4(-1e30f, -1e30f, -1e30f, -1e30f);
    float4 s4 = make_float4(0.f, 0.f, 0.f, 0.f);
    float accx = 0.f, accy = 0.f;

    for (int base = beg; base < end; base += 64) {
        int cnt = end - base; if (cnt > 64) cnt = 64;
        int sidx = 0;
        float4 e4 = make_float4(-1e30f, -1e30f, -1e30f, -1e30f);
        if (lane < cnt) {
            sidx = col[base + lane];
            float4 av = *(const float4*)&asrc[sidx * 4];
            float ex = av.x + ad4.x, ey = av.y + ad4.y,
                  ez = av.z + ad4.z, ew = av.w + ad4.w;
            e4.x = (ex > 0.f) ? ex : NEG * ex;
            e4.y = (ey > 0.f) ? ey : NEG * ey;
            e4.z = (ez > 0.f) ? ez : NEG * ez;
            e4.w = (ew > 0.f) ? ew : NEG * ew;
        }
        scol[wave][lane] = sidx;
        float4 M4 = e4;
#pragma unroll
        for (int s = 1; s < 64; s <<= 1) {
            M4.x = fmaxf(M4.x, __shfl_xor(M4.x, s));
            M4.y = fmaxf(M4.y, __shfl_xor(M4.y, s));
            M4.z = fmaxf(M4.z, __shfl_xor(M4.z, s));
            M4.w = fmaxf(M4.w, __shfl_xor(M4.w, s));
        }
        float4 nm;
        nm.x = fmaxf(m4.x, M4.x); nm.y = fmaxf(m4.y, M4.y);
        nm.z = fmaxf(m4.z, M4.z); nm.w = fmaxf(m4.w, M4.w);
        float4 sc;
        sc.x = __expf(m4.x - nm.x); sc.y = __expf(m4.y - nm.y);
        sc.z = __expf(m4.z - nm.z); sc.w = __expf(m4.w - nm.w);
        s4.x *= sc.x; s4.y *= sc.y; s4.z *= sc.z; s4.w *= sc.w;
        float rs = selh(sc, head);
        accx *= rs; accy *= rs;
        float4 w4;
        w4.x = (lane < cnt) ? __expf(e4.x - nm.x) : 0.f;
        w4.y = (lane < cnt) ? __expf(e4.y - nm.y) : 0.f;
        w4.z = (lane < cnt) ? __expf(e4.z - nm.z) : 0.f;
        w4.w = (lane < cnt) ? __expf(e4.w - nm.w) : 0.f;
        *(float4*)&sw[wave][lane * 4] = w4;
        float4 S4 = w4;
#pragma unroll
        for (int s = 1; s < 64; s <<= 1) {
            S4.x += __shfl_xor(S4.x, s);
            S4.y += __shfl_xor(S4.y, s);
            S4.z += __shfl_xor(S4.z, s);
            S4.w += __shfl_xor(S4.w, s);
        }
        s4.x += S4.x; s4.y += S4.y; s4.z += S4.z; s4.w += S4.w;
        m4 = nm;
#pragma unroll 4
        for (int p = 0; p < cnt; p++) {
            int s = scol[wave][p];
            float wgt = sw[wave][p * 4 + head];
            float2 hv = *(const float2*)&h[(size_t)s * F + lane * 2];
            accx = fmaf(wgt, hv.x, accx);
            accy = fmaf(wgt, hv.y, accy);
        }
    }

    float ssum = selh(s4, head);
    float inv = 1.f / (ssum + 1e-16f);
    float2 b2 = *(const float2*)&bias[lane * 2];
    float ox = fmaxf(fmaf(accx, inv, b2.x), 0.f);
    float oy = fmaxf(fmaf(accy, inv, b2.y), 0.f);
    *(float2*)&xout[(size_t)n * F + lane * 2] = make_float2(ox, oy);
}

// ---------------- final linear 128 -> 32, LDS-tiled ----------------

__global__ __launch_bounds__(256) void k_fc(const float* __restrict__ X,
                                            const float* __restrict__ Wf,
                                            const float* __restrict__ bf,
                                            float* __restrict__ out) {
    __shared__ float Xs[64 * 132];    // 33.8 KB
    __shared__ float Wt[128 * 33];    // 16.9 KB, Wt[k*33+o] = Wf[o*128+k]
    int tid = threadIdx.x;
    int bm = blockIdx.x * 64;

#pragma unroll
    for (int u = 0; u < 16; u++) {
        int idx = tid + 256 * u;          // 0..4095
        int o = idx >> 7, k = idx & 127;
        Wt[k * 33 + o] = Wf[idx];
    }
#pragma unroll
    for (int u = 0; u < 8; u++) {
        int f4 = tid + 256 * u;           // 0..2047
        int r = f4 >> 5, c4 = f4 & 31;
        int n = bm + r;
        float4 v = make_float4(0.f, 0.f, 0.f, 0.f);
        if (n < N_NODES) v = *(const float4*)&X[(size_t)n * F + c4 * 4];
        *(float4*)&Xs[r * 132 + c4 * 4] = v;
    }
    __syncthreads();

    int o = tid & 31, g = tid >> 5;       // 8 groups x 8 nodes
    float acc[8];
#pragma unroll
    for (int i = 0; i < 8; i++) acc[i] = 0.f;

    for (int k = 0; k < 128; k += 4) {
        float w0 = Wt[(k + 0) * 33 + o];
        float w1 = Wt[(k + 1) * 33 + o];
        float w2 = Wt[(k + 2) * 33 + o];
        float w3 = Wt[(k + 3) * 33 + o];
#pragma unroll
        for (int i = 0; i < 8; i++) {
            float4 xv = *(float4*)&Xs[(g * 8 + i) * 132 + k];
            acc[i] += xv.x * w0 + xv.y * w1 + xv.z * w2 + xv.w * w3;
        }
    }
    float bo = bf[o];
#pragma unroll
    for (int i = 0; i < 8; i++) {
        int n = bm + g * 8 + i;
        if (n < N_NODES) out[n * 32 + o] = acc[i] + bo;
    }
}

// ---------------- launch ----------------

extern "C" void kernel_launch(void* const* d_in, const int* in_sizes, int n_in,
                              void* d_out, int out_size, void* d_ws, size_t ws_size,
                              hipStream_t stream) {
    const float* x      = (const float*)d_in[0];   // [N,128]
    const float* Ws     = (const float*)d_in[1];   // [3,128,128]
    const float* a_src  = (const float*)d_in[2];   // [3,4,32]
    const float* a_dst  = (const float*)d_in[3];   // [3,4,32]
    const float* cbias  = (const float*)d_in[4];   // [3,128]
    const float* Wf     = (const float*)d_in[5];   // [32,128]
    const float* bf     = (const float*)d_in[6];   // [32]
    const int*   ei     = (const int*)d_in[7];     // [2,800000]
    float* out = (float*)d_out;

    char* p = (char*)d_ws;
    auto carve = [&](size_t bytes) {
        char* r = p;
        p += (bytes + 255) & ~(size_t)255;
        return r;
    };
    float* xA   = (float*)carve((size_t)N_NODES * F * 4);
    float* xB   = (float*)carve((size_t)N_NODES * F * 4);
    float* hbuf = (float*)carve((size_t)N_NODES * F * 4);
    float* asrc = (float*)carve((size_t)N_NODES * NHEAD * 4);
    float* adst = (float*)carve((size_t)N_NODES * NHEAD * 4);
    int* deg    = (int*)carve((size_t)N_NODES * 4);
    int* rowptr = (int*)carve((size_t)(N_NODES + 1) * 4);
    int* cursor = (int*)carve((size_t)N_NODES * 4);
    int* bsum   = (int*)carve((size_t)SCAN_B * 4);
    int* col    = (int*)carve((size_t)ETOT * 4);

    // ---- CSR build (dst-sorted adjacency) ----
    k_zero<<<(N_NODES + 255) / 256, 256, 0, stream>>>(deg, N_NODES);
    k_deg<<<(ETOT + 255) / 256, 256, 0, stream>>>(ei, deg);
    k_scan1<<<NBLK, SCAN_B, 0, stream>>>(deg, bsum);
    k_scan2<<<1, SCAN_B, 0, stream>>>(bsum);
    k_scan3<<<NBLK, SCAN_B, 0, stream>>>(deg, bsum, rowptr, cursor);
    k_fill<<<(ETOT + 255) / 256, 256, 0, stream>>>(ei, cursor, col);

    // ---- 3 GAT layers ----
    const float* xin = x;
    float* bufs[2] = {xA, xB};
    for (int l = 0; l < 3; l++) {
        k_gemm<<<(N_NODES + GM - 1) / GM, 256, 0, stream>>>(
            xin, Ws + (size_t)l * F * F, a_src + l * F, a_dst + l * F,
            hbuf, asrc, adst);
        k_aggr<<<(N_NODES + 3) / 4, 256, 0, stream>>>(hbuf, asrc, adst, rowptr, col,
                                                      cbias + l * F, bufs[l & 1]);
        xin = bufs[l & 1];
    }

    // ---- final linear ----
    k_fc<<<(N_NODES * 32 + 255) / 256, 256, 0, stream>>>(xin, Wf, bf, out);
}

// Round 5
// 605.701 us; speedup vs baseline: 1.9816x; 1.0767x over previous
//
#include <hip/hip_runtime.h>
#include <hip/hip_bf16.h>
#include <math.h>

#define N_NODES 50000
#define NE      800000
#define ETOT    (NE + N_NODES)   // edges + self loops = 850000
#define F       128              // F_in == H*C
#define NHEAD   4
#define NEG     0.2f

#define SCAN_B 256
#define NBLK   ((N_NODES + SCAN_B - 1) / SCAN_B)   // 196

// ---------------- CSR build ----------------

__global__ void k_zero(int* __restrict__ p, int n) {
    int i = blockIdx.x * blockDim.x + threadIdx.x;
    if (i < n) p[i] = 0;
}

__global__ void k_deg(const int* __restrict__ ei, int* __restrict__ deg) {
    int i = blockIdx.x * blockDim.x + threadIdx.x;
    if (i < ETOT) {
        int d = (i < NE) ? ei[NE + i] : (i - NE);
        atomicAdd(&deg[d], 1);
    }
}

__global__ void k_scan1(const int* __restrict__ deg, int* __restrict__ bsum) {
    __shared__ int sm[SCAN_B];
    int i = blockIdx.x * SCAN_B + threadIdx.x;
    sm[threadIdx.x] = (i < N_NODES) ? deg[i] : 0;
    __syncthreads();
    for (int s = SCAN_B / 2; s > 0; s >>= 1) {
        if (threadIdx.x < s) sm[threadIdx.x] += sm[threadIdx.x + s];
        __syncthreads();
    }
    if (threadIdx.x == 0) bsum[blockIdx.x] = sm[0];
}

__global__ void k_scan2(int* __restrict__ bsum) {
    __shared__ int sm[SCAN_B];
    int t = threadIdx.x;
    int v = (t < NBLK) ? bsum[t] : 0;
    sm[t] = v; __syncthreads();
    for (int s = 1; s < SCAN_B; s <<= 1) {
        int a = (t >= s) ? sm[t - s] : 0;
        __syncthreads();
        sm[t] += a;
        __syncthreads();
    }
    if (t < NBLK) bsum[t] = sm[t] - v;  // exclusive
}

__global__ void k_scan3(const int* __restrict__ deg, const int* __restrict__ bsum,
                        int* __restrict__ rowptr, int* __restrict__ cursor) {
    __shared__ int sm[SCAN_B];
    int t = threadIdx.x;
    int i = blockIdx.x * SCAN_B + t;
    int v = (i < N_NODES) ? deg[i] : 0;
    sm[t] = v; __syncthreads();
    for (int s = 1; s < SCAN_B; s <<= 1) {
        int a = (t >= s) ? sm[t - s] : 0;
        __syncthreads();
        sm[t] += a;
        __syncthreads();
    }
    int excl = sm[t] - v + bsum[blockIdx.x];
    if (i < N_NODES) { rowptr[i] = excl; cursor[i] = excl; }
    if (i == N_NODES - 1) rowptr[N_NODES] = excl + v;
}

__global__ void k_fill(const int* __restrict__ ei, int* __restrict__ cursor,
                       int* __restrict__ col) {
    int i = blockIdx.x * blockDim.x + threadIdx.x;
    if (i < ETOT) {
        int s, d;
        if (i < NE) { s = ei[i]; d = ei[NE + i]; }
        else        { s = i - NE; d = s; }
        int pos = atomicAdd(&cursor[d], 1);
        col[pos] = s;
    }
}

// ---------------- GEMM + fused alpha: h = X @ W^T, asrc/adst per node/head ----
// 64 nodes/block, 256 threads, each thread 4 nodes x 8 j (j = tx + jj*16).
// NOTE: plain __launch_bounds__(256). The (256,3) variant made the allocator
// target ~84 VGPRs -> acc spilled to scratch in the inner loop -> 585 MB
// WRITE_SIZE and 277 us/dispatch (round-3 counters). Do not add a 2nd arg.

#define GM 64
#define KT 32
#define LPAD 36

__global__ __launch_bounds__(256) void k_gemm(const float* __restrict__ X,
                                              const float* __restrict__ W,
                                              const float* __restrict__ a_s,
                                              const float* __restrict__ a_d,
                                              float* __restrict__ hout,
                                              float* __restrict__ asrc,
                                              float* __restrict__ adst) {
    __shared__ float Xs[GM * LPAD];
    __shared__ float Wsh[F * LPAD];
    int tid = threadIdx.x;
    int tx = tid & 15;    // j = tx + jj*16
    int ty = tid >> 4;    // nodes ty*4 .. ty*4+3
    int bm = blockIdx.x * GM;

    float acc[4][8];
#pragma unroll
    for (int i = 0; i < 4; i++)
#pragma unroll
        for (int j = 0; j < 8; j++) acc[i][j] = 0.f;

    for (int k0 = 0; k0 < F; k0 += KT) {
        // stage X tile: 64x32 floats = 512 float4, 2 per thread
#pragma unroll
        for (int u = 0; u < 2; u++) {
            int f4 = tid + 256 * u;
            int r = f4 >> 3, c4 = f4 & 7;
            int gr = bm + r;
            float4 v = make_float4(0.f, 0.f, 0.f, 0.f);
            if (gr < N_NODES) v = *(const float4*)&X[(size_t)gr * F + k0 + c4 * 4];
            *(float4*)&Xs[r * LPAD + c4 * 4] = v;
        }
        // stage W tile: 128x32 floats = 1024 float4, 4 per thread
#pragma unroll
        for (int u = 0; u < 4; u++) {
            int f4 = tid + 256 * u;
            int r = f4 >> 3, c4 = f4 & 7;
            *(float4*)&Wsh[r * LPAD + c4 * 4] = *(const float4*)&W[r * F + k0 + c4 * 4];
        }
        __syncthreads();

#pragma unroll
        for (int kk = 0; kk < KT; kk += 4) {
            float4 xv[4], wv[8];
#pragma unroll
            for (int i = 0; i < 4; i++) xv[i] = *(float4*)&Xs[(ty * 4 + i) * LPAD + kk];
#pragma unroll
            for (int j = 0; j < 8; j++) wv[j] = *(float4*)&Wsh[(tx + j * 16) * LPAD + kk];
#pragma unroll
            for (int i = 0; i < 4; i++)
#pragma unroll
                for (int j = 0; j < 8; j++)
                    acc[i][j] += xv[i].x * wv[j].x + xv[i].y * wv[j].y
                               + xv[i].z * wv[j].z + xv[i].w * wv[j].w;
        }
        __syncthreads();
    }

    // epilogue: store h + fused per-node attention logits
    float as_v[8], ad_v[8];
#pragma unroll
    for (int jj = 0; jj < 8; jj++) {
        as_v[jj] = a_s[tx + jj * 16];
        ad_v[jj] = a_d[tx + jj * 16];
    }
#pragma unroll
    for (int i = 0; i < 4; i++) {
        int n = bm + ty * 4 + i;
        bool ok = (n < N_NODES);
        if (ok) {
#pragma unroll
            for (int jj = 0; jj < 8; jj++) hout[(size_t)n * F + tx + jj * 16] = acc[i][jj];
        }
        float ps[4], pd[4];
#pragma unroll
        for (int hh = 0; hh < 4; hh++) {
            ps[hh] = acc[i][2 * hh] * as_v[2 * hh] + acc[i][2 * hh + 1] * as_v[2 * hh + 1];
            pd[hh] = acc[i][2 * hh] * ad_v[2 * hh] + acc[i][2 * hh + 1] * ad_v[2 * hh + 1];
        }
#pragma unroll
        for (int s = 1; s < 16; s <<= 1) {
#pragma unroll
            for (int hh = 0; hh < 4; hh++) {
                ps[hh] += __shfl_xor(ps[hh], s);
                pd[hh] += __shfl_xor(pd[hh], s);
            }
        }
        if (ok && tx == 0) {
            *(float4*)&asrc[n * 4] = make_float4(ps[0], ps[1], ps[2], ps[3]);
            *(float4*)&adst[n * 4] = make_float4(pd[0], pd[1], pd[2], pd[3]);
        }
    }
}

// ---------------- fused softmax + aggregate, one wave per dst node ----------------

__device__ __forceinline__ float selh(float4 v, int h) {
    float r = v.x;
    r = (h == 1) ? v.y : r;
    r = (h == 2) ? v.z : r;
    r = (h == 3) ? v.w : r;
    return r;
}

__global__ __launch_bounds__(256) void k_aggr(const float* __restrict__ h,
                                              const float* __restrict__ asrc,
                                              const float* __restrict__ adst,
                                              const int* __restrict__ rowptr,
                                              const int* __restrict__ col,
                                              const float* __restrict__ bias,
                                              float* __restrict__ xout) {
    __shared__ int   scol[4][64];
    __shared__ float sw[4][64 * 4];
    int wave = threadIdx.x >> 6;
    int lane = threadIdx.x & 63;
    int n = blockIdx.x * 4 + wave;
    if (n >= N_NODES) return;
    int head = lane >> 4;                // lane owns channels 2*lane, 2*lane+1
    int beg = rowptr[n], end = rowptr[n + 1];
    float4 ad4 = *(const float4*)&adst[n * 4];

    float4 m4 = make_float4(-1e30f, -1e30f, -1e30f, -1e30f);
    float4 s4 = make_float4(0.f, 0.f, 0.f, 0.f);
    float accx = 0.f, accy = 0.f;

    for (int base = beg; base < end; base += 64) {
        int cnt = end - base; if (cnt > 64) cnt = 64;
        int sidx = 0;
        float4 e4 = make_float4(-1e30f, -1e30f, -1e30f, -1e30f);
        if (lane < cnt) {
            sidx = col[base + lane];
            float4 av = *(const float4*)&asrc[sidx * 4];
            float ex = av.x + ad4.x, ey = av.y + ad4.y,
                  ez = av.z + ad4.z, ew = av.w + ad4.w;
            e4.x = (ex > 0.f) ? ex : NEG * ex;
            e4.y = (ey > 0.f) ? ey : NEG * ey;
            e4.z = (ez > 0.f) ? ez : NEG * ez;
            e4.w = (ew > 0.f) ? ew : NEG * ew;
        }
        scol[wave][lane] = sidx;
        float4 M4 = e4;
#pragma unroll
        for (int s = 1; s < 64; s <<= 1) {
            M4.x = fmaxf(M4.x, __shfl_xor(M4.x, s));
            M4.y = fmaxf(M4.y, __shfl_xor(M4.y, s));
            M4.z = fmaxf(M4.z, __shfl_xor(M4.z, s));
            M4.w = fmaxf(M4.w, __shfl_xor(M4.w, s));
        }
        float4 nm;
        nm.x = fmaxf(m4.x, M4.x); nm.y = fmaxf(m4.y, M4.y);
        nm.z = fmaxf(m4.z, M4.z); nm.w = fmaxf(m4.w, M4.w);
        float4 sc;
        sc.x = __expf(m4.x - nm.x); sc.y = __expf(m4.y - nm.y);
        sc.z = __expf(m4.z - nm.z); sc.w = __expf(m4.w - nm.w);
        s4.x *= sc.x; s4.y *= sc.y; s4.z *= sc.z; s4.w *= sc.w;
        float rs = selh(sc, head);
        accx *= rs; accy *= rs;
        float4 w4;
        w4.x = (lane < cnt) ? __expf(e4.x - nm.x) : 0.f;
        w4.y = (lane < cnt) ? __expf(e4.y - nm.y) : 0.f;
        w4.z = (lane < cnt) ? __expf(e4.z - nm.z) : 0.f;
        w4.w = (lane < cnt) ? __expf(e4.w - nm.w) : 0.f;
        *(float4*)&sw[wave][lane * 4] = w4;
        float4 S4 = w4;
#pragma unroll
        for (int s = 1; s < 64; s <<= 1) {
            S4.x += __shfl_xor(S4.x, s);
            S4.y += __shfl_xor(S4.y, s);
            S4.z += __shfl_xor(S4.z, s);
            S4.w += __shfl_xor(S4.w, s);
        }
        s4.x += S4.x; s4.y += S4.y; s4.z += S4.z; s4.w += S4.w;
        m4 = nm;
        // pipelined feature gather; unroll 8 for memory-level parallelism
#pragma unroll 8
        for (int p = 0; p < cnt; p++) {
            int s = scol[wave][p];
            float wgt = sw[wave][p * 4 + head];
            float2 hv = *(const float2*)&h[(size_t)s * F + lane * 2];
            accx = fmaf(wgt, hv.x, accx);
            accy = fmaf(wgt, hv.y, accy);
        }
    }

    float ssum = selh(s4, head);
    float inv = 1.f / (ssum + 1e-16f);
    float2 b2 = *(const float2*)&bias[lane * 2];
    float ox = fmaxf(fmaf(accx, inv, b2.x), 0.f);
    float oy = fmaxf(fmaf(accy, inv, b2.y), 0.f);
    *(float2*)&xout[(size_t)n * F + lane * 2] = make_float2(ox, oy);
}

// ---------------- final linear 128 -> 32: register-blocked GEMM ----------------
// 128 nodes/block, 256 threads. Transposed LDS tiles: XsT[k][n], WsT[k][o].
// Thread (tx=tid&7, ty=tid>>3) owns 4 nodes x 4 outputs; per k it reads ONE
// b128 for 4 nodes + ONE b128 for 4 outputs feeding 16 FMAs (8:1 FMA:LDS vs
// 2.7:1 in the round-4 version that ran LDS-pipe-bound at 96us).
// Bank check: XsT addr ty*4 spreads all 32 banks; WsT addr tx*4 spreads 8
// bank-groups; both conflict-free.

#define FCB 128

__global__ __launch_bounds__(256) void k_fc(const float* __restrict__ X,
                                            const float* __restrict__ Wf,
                                            const float* __restrict__ bf,
                                            float* __restrict__ out) {
    __shared__ float WsT[128 * 36];   // [k][o], 18.4 KB, staged once
    __shared__ float XsT[32 * 132];   // [k][n] per 32-k chunk, 16.9 KB
    int tid = threadIdx.x;
    int bm = blockIdx.x * FCB;

    // stage WsT[k*36+o] = Wf[o*128+k] (coalesced read, scattered LDS write)
#pragma unroll
    for (int u = 0; u < 16; u++) {
        int idx = tid + 256 * u;          // 0..4095
        int o = idx >> 7, k = idx & 127;
        WsT[k * 36 + o] = Wf[idx];
    }

    int tx = tid & 7;      // outputs tx*4 .. tx*4+3
    int ty = tid >> 3;     // nodes ty*4 .. ty*4+3
    float acc[4][4];
#pragma unroll
    for (int i = 0; i < 4; i++)
#pragma unroll
        for (int j = 0; j < 4; j++) acc[i][j] = 0.f;

    for (int k0 = 0; k0 < 128; k0 += 32) {
        __syncthreads();   // protects WsT (first iter) and previous XsT reads
        // stage XsT: coalesced float4 read of X, transpose-scatter into LDS
#pragma unroll
        for (int u = 0; u < 4; u++) {
            int f4 = tid + 256 * u;       // 0..1023 = 128 nodes x 8 float4
            int r = f4 >> 3, c4 = f4 & 7;
            int n = bm + r;
            float4 v = make_float4(0.f, 0.f, 0.f, 0.f);
            if (n < N_NODES) v = *(const float4*)&X[(size_t)n * F + k0 + c4 * 4];
            XsT[(c4 * 4 + 0) * 132 + r] = v.x;
            XsT[(c4 * 4 + 1) * 132 + r] = v.y;
            XsT[(c4 * 4 + 2) * 132 + r] = v.z;
            XsT[(c4 * 4 + 3) * 132 + r] = v.w;
        }
        __syncthreads();

#pragma unroll
        for (int kk = 0; kk < 32; kk++) {
            float4 xv = *(float4*)&XsT[kk * 132 + ty * 4];
            float4 wv = *(float4*)&WsT[(k0 + kk) * 36 + tx * 4];
            float xs[4] = {xv.x, xv.y, xv.z, xv.w};
            float ws[4] = {wv.x, wv.y, wv.z, wv.w};
#pragma unroll
            for (int i = 0; i < 4; i++)
#pragma unroll
                for (int j = 0; j < 4; j++)
                    acc[i][j] = fmaf(xs[i], ws[j], acc[i][j]);
        }
    }

    float4 bv = *(const float4*)&bf[tx * 4];
#pragma unroll
    for (int i = 0; i < 4; i++) {
        int n = bm + ty * 4 + i;
        if (n < N_NODES) {
            float4 o4 = make_float4(acc[i][0] + bv.x, acc[i][1] + bv.y,
                                    acc[i][2] + bv.z, acc[i][3] + bv.w);
            *(float4*)&out[n * 32 + tx * 4] = o4;
        }
    }
}

// ---------------- launch ----------------

extern "C" void kernel_launch(void* const* d_in, const int* in_sizes, int n_in,
                              void* d_out, int out_size, void* d_ws, size_t ws_size,
                              hipStream_t stream) {
    const float* x      = (const float*)d_in[0];   // [N,128]
    const float* Ws     = (const float*)d_in[1];   // [3,128,128]
    const float* a_src  = (const float*)d_in[2];   // [3,4,32]
    const float* a_dst  = (const float*)d_in[3];   // [3,4,32]
    const float* cbias  = (const float*)d_in[4];   // [3,128]
    const float* Wf     = (const float*)d_in[5];   // [32,128]
    const float* bf     = (const float*)d_in[6];   // [32]
    const int*   ei     = (const int*)d_in[7];     // [2,800000]
    float* out = (float*)d_out;

    char* p = (char*)d_ws;
    auto carve = [&](size_t bytes) {
        char* r = p;
        p += (bytes + 255) & ~(size_t)255;
        return r;
    };
    float* xA   = (float*)carve((size_t)N_NODES * F * 4);
    float* xB   = (float*)carve((size_t)N_NODES * F * 4);
    float* hbuf = (float*)carve((size_t)N_NODES * F * 4);
    float* asrc = (float*)carve((size_t)N_NODES * NHEAD * 4);
    float* adst = (float*)carve((size_t)N_NODES * NHEAD * 4);
    int* deg    = (int*)carve((size_t)N_NODES * 4);
    int* rowptr = (int*)carve((size_t)(N_NODES + 1) * 4);
    int* cursor = (int*)carve((size_t)N_NODES * 4);
    int* bsum   = (int*)carve((size_t)SCAN_B * 4);
    int* col    = (int*)carve((size_t)ETOT * 4);

    // ---- CSR build (dst-sorted adjacency) ----
    k_zero<<<(N_NODES + 255) / 256, 256, 0, stream>>>(deg, N_NODES);
    k_deg<<<(ETOT + 255) / 256, 256, 0, stream>>>(ei, deg);
    k_scan1<<<NBLK, SCAN_B, 0, stream>>>(deg, bsum);
    k_scan2<<<1, SCAN_B, 0, stream>>>(bsum);
    k_scan3<<<NBLK, SCAN_B, 0, stream>>>(deg, bsum, rowptr, cursor);
    k_fill<<<(ETOT + 255) / 256, 256, 0, stream>>>(ei, cursor, col);

    // ---- 3 GAT layers ----
    const float* xin = x;
    float* bufs[2] = {xA, xB};
    for (int l = 0; l < 3; l++) {
        k_gemm<<<(N_NODES + GM - 1) / GM, 256, 0, stream>>>(
            xin, Ws + (size_t)l * F * F, a_src + l * F, a_dst + l * F,
            hbuf, asrc, adst);
        k_aggr<<<(N_NODES + 3) / 4, 256, 0, stream>>>(hbuf, asrc, adst, rowptr, col,
                                                      cbias + l * F, bufs[l & 1]);
        xin = bufs[l & 1];
    }

    // ---- final linear ----
    k_fc<<<(N_NODES + FCB - 1) / FCB, 256, 0, stream>>>(xin, Wf, bf, out);
}

// Round 6
// 495.573 us; speedup vs baseline: 2.4219x; 1.2222x over previous
//
#include <hip/hip_runtime.h>
#include <hip/hip_bf16.h>
#include <math.h>

#define N_NODES 50000
#define NE      800000
#define ETOT    (NE + N_NODES)   // edges + self loops = 850000
#define F       128              // F_in == H*C
#define NHEAD   4
#define NEG     0.2f

#define SCAN_B 256
#define NBLK   ((N_NODES + SCAN_B - 1) / SCAN_B)   // 196

typedef __attribute__((ext_vector_type(8))) short bf16x8;
typedef __attribute__((ext_vector_type(4))) float f32x4;

// ---------------- CSR build ----------------

__global__ void k_zero(int* __restrict__ p, int n) {
    int i = blockIdx.x * blockDim.x + threadIdx.x;
    if (i < n) p[i] = 0;
}

__global__ void k_deg(const int* __restrict__ ei, int* __restrict__ deg) {
    int i = blockIdx.x * blockDim.x + threadIdx.x;
    if (i < ETOT) {
        int d = (i < NE) ? ei[NE + i] : (i - NE);
        atomicAdd(&deg[d], 1);
    }
}

__global__ void k_scan1(const int* __restrict__ deg, int* __restrict__ bsum) {
    __shared__ int sm[SCAN_B];
    int i = blockIdx.x * SCAN_B + threadIdx.x;
    sm[threadIdx.x] = (i < N_NODES) ? deg[i] : 0;
    __syncthreads();
    for (int s = SCAN_B / 2; s > 0; s >>= 1) {
        if (threadIdx.x < s) sm[threadIdx.x] += sm[threadIdx.x + s];
        __syncthreads();
    }
    if (threadIdx.x == 0) bsum[blockIdx.x] = sm[0];
}

__global__ void k_scan2(int* __restrict__ bsum) {
    __shared__ int sm[SCAN_B];
    int t = threadIdx.x;
    int v = (t < NBLK) ? bsum[t] : 0;
    sm[t] = v; __syncthreads();
    for (int s = 1; s < SCAN_B; s <<= 1) {
        int a = (t >= s) ? sm[t - s] : 0;
        __syncthreads();
        sm[t] += a;
        __syncthreads();
    }
    if (t < NBLK) bsum[t] = sm[t] - v;  // exclusive
}

__global__ void k_scan3(const int* __restrict__ deg, const int* __restrict__ bsum,
                        int* __restrict__ rowptr, int* __restrict__ cursor) {
    __shared__ int sm[SCAN_B];
    int t = threadIdx.x;
    int i = blockIdx.x * SCAN_B + t;
    int v = (i < N_NODES) ? deg[i] : 0;
    sm[t] = v; __syncthreads();
    for (int s = 1; s < SCAN_B; s <<= 1) {
        int a = (t >= s) ? sm[t - s] : 0;
        __syncthreads();
        sm[t] += a;
        __syncthreads();
    }
    int excl = sm[t] - v + bsum[blockIdx.x];
    if (i < N_NODES) { rowptr[i] = excl; cursor[i] = excl; }
    if (i == N_NODES - 1) rowptr[N_NODES] = excl + v;
}

__global__ void k_fill(const int* __restrict__ ei, int* __restrict__ cursor,
                       int* __restrict__ col) {
    int i = blockIdx.x * blockDim.x + threadIdx.x;
    if (i < ETOT) {
        int s, d;
        if (i < NE) { s = ei[i]; d = ei[NE + i]; }
        else        { s = i - NE; d = s; }
        int pos = atomicAdd(&cursor[d], 1);
        col[pos] = s;
    }
}

// ---------------- split-bf16 helpers ----------------

__device__ __forceinline__ unsigned short f2bf(float x) {   // RNE truncate
    unsigned int u = __float_as_uint(x);
    u += 0x7FFFu + ((u >> 16) & 1u);
    return (unsigned short)(u >> 16);
}
__device__ __forceinline__ float bf2f(unsigned short h) {
    return __uint_as_float(((unsigned int)h) << 16);
}
__device__ __forceinline__ void cvt8(float4 a, float4 b, bf16x8* hi, bf16x8* lo) {
    float f[8] = {a.x, a.y, a.z, a.w, b.x, b.y, b.z, b.w};
    bf16x8 h, l;
#pragma unroll
    for (int j = 0; j < 8; j++) {
        unsigned short hu = f2bf(f[j]);
        h[j] = (short)hu;
        l[j] = (short)f2bf(f[j] - bf2f(hu));
    }
    *hi = h; *lo = l;
}

// ---------------- GEMM via split-bf16 MFMA + fused alpha ----------------
// h = X @ W^T. 64 nodes/block, 256 threads = 4 waves; wave w owns rows
// w*16..w*16+15, all 128 outputs (8 n-tiles of 16). Per 32-k tile, each
// fp32 operand is split hi+lo bf16; A*B ~= Ah*Bh + Ah*Bl + Al*Bh (3 MFMAs,
// dropped Al*Bl ~ 2^-16 rel). LDS stores 16B units (8 bf16) XOR-swizzled:
// unit(m,q) = 4m + (q ^ ((m>>1)&3))  ->  <=2-way bank aliasing (free, m136).
// Fragment layouts (m89/m120): A[m=lane&15][k=quad*8+j]; B[n=lane&15][k=..];
// C/D col=lane&15, row=quad*4+reg. Global loads for tile t+1 prefetched into
// registers during compute of tile t. Plain launch_bounds (round-3 lesson:
// a 2nd arg forces spills).

#define GM 64

__device__ __forceinline__ int lds_unit(int m, int q) {
    return 4 * m + (q ^ ((m >> 1) & 3));
}

__global__ __launch_bounds__(256) void k_gemm(const float* __restrict__ X,
                                              const float* __restrict__ W,
                                              const float* __restrict__ a_s,
                                              const float* __restrict__ a_d,
                                              float* __restrict__ hout,
                                              float* __restrict__ asrc,
                                              float* __restrict__ adst) {
    __shared__ short Ah[256 * 8], Al[256 * 8];    // 64 rows x 4 units, 4KB each
    __shared__ short Bh[512 * 8], Bl[512 * 8];    // 128 rows x 4 units, 8KB each
    int tid = threadIdx.x;
    int bm = blockIdx.x * GM;

    // staging coords: X unit = (row am, quad aq); W units tid and tid+256
    int am = tid >> 2, aq = tid & 3;
    int xunit = ((am >> 4) << 6) + lds_unit(am & 15, aq);
    int wj = tid >> 2, wq = tid & 3;
    int wunit = ((wj >> 4) << 6) + lds_unit(wj & 15, wq);   // second = wunit+256

    // fragment coords
    int lane = tid & 63, wv = tid >> 6;
    int fm = lane & 15, fq = lane >> 4;
    int a_unit = (wv << 6) + lds_unit(fm, fq);
    int b_unit0 = lds_unit(fm, fq);

    f32x4 acc[8];
#pragma unroll
    for (int nt = 0; nt < 8; nt++) acc[nt] = (f32x4){0.f, 0.f, 0.f, 0.f};

    float4 xp0, xp1, wp0, wp1, wp2, wp3;
    int gr = bm + am;
    bool xok = (gr < N_NODES);
    const float* xrow = X + (size_t)gr * F + aq * 8;
    const float* wrow1 = W + (size_t)wj * F + wq * 8;
    const float* wrow2 = W + (size_t)(wj + 64) * F + wq * 8;
    float4 z4 = make_float4(0.f, 0.f, 0.f, 0.f);

    auto load_tile = [&](int k0) {
        xp0 = xok ? *(const float4*)(xrow + k0)     : z4;
        xp1 = xok ? *(const float4*)(xrow + k0 + 4) : z4;
        wp0 = *(const float4*)(wrow1 + k0);
        wp1 = *(const float4*)(wrow1 + k0 + 4);
        wp2 = *(const float4*)(wrow2 + k0);
        wp3 = *(const float4*)(wrow2 + k0 + 4);
    };
    auto store_tile = [&]() {
        bf16x8 hi, lo;
        cvt8(xp0, xp1, &hi, &lo);
        *(bf16x8*)&Ah[xunit * 8] = hi;  *(bf16x8*)&Al[xunit * 8] = lo;
        cvt8(wp0, wp1, &hi, &lo);
        *(bf16x8*)&Bh[wunit * 8] = hi;  *(bf16x8*)&Bl[wunit * 8] = lo;
        cvt8(wp2, wp3, &hi, &lo);
        *(bf16x8*)&Bh[(wunit + 256) * 8] = hi;  *(bf16x8*)&Bl[(wunit + 256) * 8] = lo;
    };

    load_tile(0);
    store_tile();
    __syncthreads();

#pragma unroll
    for (int t = 0; t < 4; t++) {
        if (t < 3) load_tile((t + 1) * 32);     // prefetch overlaps compute
        bf16x8 ah = *(bf16x8*)&Ah[a_unit * 8];
        bf16x8 al = *(bf16x8*)&Al[a_unit * 8];
#pragma unroll
        for (int nt = 0; nt < 8; nt++) {
            int bu = ((nt << 6) + b_unit0) * 8;
            bf16x8 bh = *(bf16x8*)&Bh[bu];
            bf16x8 bl = *(bf16x8*)&Bl[bu];
            acc[nt] = __builtin_amdgcn_mfma_f32_16x16x32_bf16(ah, bh, acc[nt], 0, 0, 0);
            acc[nt] = __builtin_amdgcn_mfma_f32_16x16x32_bf16(ah, bl, acc[nt], 0, 0, 0);
            acc[nt] = __builtin_amdgcn_mfma_f32_16x16x32_bf16(al, bh, acc[nt], 0, 0, 0);
        }
        __syncthreads();
        if (t < 3) { store_tile(); __syncthreads(); }
    }

    // epilogue: store h + fused per-node attention logits
    float as_v[8], ad_v[8];
#pragma unroll
    for (int nt = 0; nt < 8; nt++) {
        as_v[nt] = a_s[nt * 16 + fm];
        ad_v[nt] = a_d[nt * 16 + fm];
    }
#pragma unroll
    for (int r = 0; r < 4; r++) {
        int n = bm + wv * 16 + fq * 4 + r;
        bool ok = (n < N_NODES);
        if (ok) {
#pragma unroll
            for (int nt = 0; nt < 8; nt++)
                hout[(size_t)n * F + nt * 16 + fm] = acc[nt][r];
        }
        float ps[4], pd[4];
#pragma unroll
        for (int hh = 0; hh < 4; hh++) {
            ps[hh] = acc[2 * hh][r] * as_v[2 * hh] + acc[2 * hh + 1][r] * as_v[2 * hh + 1];
            pd[hh] = acc[2 * hh][r] * ad_v[2 * hh] + acc[2 * hh + 1][r] * ad_v[2 * hh + 1];
        }
#pragma unroll
        for (int s = 1; s < 16; s <<= 1) {
#pragma unroll
            for (int hh = 0; hh < 4; hh++) {
                ps[hh] += __shfl_xor(ps[hh], s);
                pd[hh] += __shfl_xor(pd[hh], s);
            }
        }
        if (ok && fm == 0) {
            *(float4*)&asrc[n * 4] = make_float4(ps[0], ps[1], ps[2], ps[3]);
            *(float4*)&adst[n * 4] = make_float4(pd[0], pd[1], pd[2], pd[3]);
        }
    }
}

// ---------------- fused softmax + aggregate, one wave per dst node ----------------

__device__ __forceinline__ float selh(float4 v, int h) {
    float r = v.x;
    r = (h == 1) ? v.y : r;
    r = (h == 2) ? v.z : r;
    r = (h == 3) ? v.w : r;
    return r;
}

__global__ __launch_bounds__(256) void k_aggr(const float* __restrict__ h,
                                              const float* __restrict__ asrc,
                                              const float* __restrict__ adst,
                                              const int* __restrict__ rowptr,
                                              const int* __restrict__ col,
                                              const float* __restrict__ bias,
                                              float* __restrict__ xout) {
    __shared__ int   scol[4][64];
    __shared__ float sw[4][64 * 4];
    int wave = threadIdx.x >> 6;
    int lane = threadIdx.x & 63;
    int n = blockIdx.x * 4 + wave;
    if (n >= N_NODES) return;
    int head = lane >> 4;                // lane owns channels 2*lane, 2*lane+1
    int beg = rowptr[n], end = rowptr[n + 1];
    float4 ad4 = *(const float4*)&adst[n * 4];

    float4 m4 = make_float4(-1e30f, -1e30f, -1e30f, -1e30f);
    float4 s4 = make_float4(0.f, 0.f, 0.f, 0.f);
    float accx = 0.f, accy = 0.f;

    for (int base = beg; base < end; base += 64) {
        int cnt = end - base; if (cnt > 64) cnt = 64;
        int sidx = 0;
        float4 e4 = make_float4(-1e30f, -1e30f, -1e30f, -1e30f);
        if (lane < cnt) {
            sidx = col[base + lane];
            float4 av = *(const float4*)&asrc[sidx * 4];
            float ex = av.x + ad4.x, ey = av.y + ad4.y,
                  ez = av.z + ad4.z, ew = av.w + ad4.w;
            e4.x = (ex > 0.f) ? ex : NEG * ex;
            e4.y = (ey > 0.f) ? ey : NEG * ey;
            e4.z = (ez > 0.f) ? ez : NEG * ez;
            e4.w = (ew > 0.f) ? ew : NEG * ew;
        }
        scol[wave][lane] = sidx;
        float4 M4 = e4;
#pragma unroll
        for (int s = 1; s < 64; s <<= 1) {
            M4.x = fmaxf(M4.x, __shfl_xor(M4.x, s));
            M4.y = fmaxf(M4.y, __shfl_xor(M4.y, s));
            M4.z = fmaxf(M4.z, __shfl_xor(M4.z, s));
            M4.w = fmaxf(M4.w, __shfl_xor(M4.w, s));
        }
        float4 nm;
        nm.x = fmaxf(m4.x, M4.x); nm.y = fmaxf(m4.y, M4.y);
        nm.z = fmaxf(m4.z, M4.z); nm.w = fmaxf(m4.w, M4.w);
        float4 sc;
        sc.x = __expf(m4.x - nm.x); sc.y = __expf(m4.y - nm.y);
        sc.z = __expf(m4.z - nm.z); sc.w = __expf(m4.w - nm.w);
        s4.x *= sc.x; s4.y *= sc.y; s4.z *= sc.z; s4.w *= sc.w;
        float rs = selh(sc, head);
        accx *= rs; accy *= rs;
        float4 w4;
        w4.x = (lane < cnt) ? __expf(e4.x - nm.x) : 0.f;
        w4.y = (lane < cnt) ? __expf(e4.y - nm.y) : 0.f;
        w4.z = (lane < cnt) ? __expf(e4.z - nm.z) : 0.f;
        w4.w = (lane < cnt) ? __expf(e4.w - nm.w) : 0.f;
        *(float4*)&sw[wave][lane * 4] = w4;
        float4 S4 = w4;
#pragma unroll
        for (int s = 1; s < 64; s <<= 1) {
            S4.x += __shfl_xor(S4.x, s);
            S4.y += __shfl_xor(S4.y, s);
            S4.z += __shfl_xor(S4.z, s);
            S4.w += __shfl_xor(S4.w, s);
        }
        s4.x += S4.x; s4.y += S4.y; s4.z += S4.z; s4.w += S4.w;
        m4 = nm;
        // pipelined feature gather; unroll 8 for memory-level parallelism
#pragma unroll 8
        for (int p = 0; p < cnt; p++) {
            int s = scol[wave][p];
            float wgt = sw[wave][p * 4 + head];
            float2 hv = *(const float2*)&h[(size_t)s * F + lane * 2];
            accx = fmaf(wgt, hv.x, accx);
            accy = fmaf(wgt, hv.y, accy);
        }
    }

    float ssum = selh(s4, head);
    float inv = 1.f / (ssum + 1e-16f);
    float2 b2 = *(const float2*)&bias[lane * 2];
    float ox = fmaxf(fmaf(accx, inv, b2.x), 0.f);
    float oy = fmaxf(fmaf(accy, inv, b2.y), 0.f);
    *(float2*)&xout[(size_t)n * F + lane * 2] = make_float2(ox, oy);
}

// ---------------- final linear 128 -> 32: register-blocked GEMM ----------------

#define FCB 128

__global__ __launch_bounds__(256) void k_fc(const float* __restrict__ X,
                                            const float* __restrict__ Wf,
                                            const float* __restrict__ bf,
                                            float* __restrict__ out) {
    __shared__ float WsT[128 * 36];   // [k][o], staged once
    __shared__ float XsT[32 * 132];   // [k][n] per 32-k chunk
    int tid = threadIdx.x;
    int bm = blockIdx.x * FCB;

#pragma unroll
    for (int u = 0; u < 16; u++) {
        int idx = tid + 256 * u;          // 0..4095
        int o = idx >> 7, k = idx & 127;
        WsT[k * 36 + o] = Wf[idx];
    }

    int tx = tid & 7;      // outputs tx*4 .. tx*4+3
    int ty = tid >> 3;     // nodes ty*4 .. ty*4+3
    float acc[4][4];
#pragma unroll
    for (int i = 0; i < 4; i++)
#pragma unroll
        for (int j = 0; j < 4; j++) acc[i][j] = 0.f;

    for (int k0 = 0; k0 < 128; k0 += 32) {
        __syncthreads();
#pragma unroll
        for (int u = 0; u < 4; u++) {
            int f4 = tid + 256 * u;       // 0..1023 = 128 nodes x 8 float4
            int r = f4 >> 3, c4 = f4 & 7;
            int n = bm + r;
            float4 v = make_float4(0.f, 0.f, 0.f, 0.f);
            if (n < N_NODES) v = *(const float4*)&X[(size_t)n * F + k0 + c4 * 4];
            XsT[(c4 * 4 + 0) * 132 + r] = v.x;
            XsT[(c4 * 4 + 1) * 132 + r] = v.y;
            XsT[(c4 * 4 + 2) * 132 + r] = v.z;
            XsT[(c4 * 4 + 3) * 132 + r] = v.w;
        }
        __syncthreads();

#pragma unroll
        for (int kk = 0; kk < 32; kk++) {
            float4 xv = *(float4*)&XsT[kk * 132 + ty * 4];
            float4 wv = *(float4*)&WsT[(k0 + kk) * 36 + tx * 4];
            float xs[4] = {xv.x, xv.y, xv.z, xv.w};
            float ws[4] = {wv.x, wv.y, wv.z, wv.w};
#pragma unroll
            for (int i = 0; i < 4; i++)
#pragma unroll
                for (int j = 0; j < 4; j++)
                    acc[i][j] = fmaf(xs[i], ws[j], acc[i][j]);
        }
    }

    float4 bv = *(const float4*)&bf[tx * 4];
#pragma unroll
    for (int i = 0; i < 4; i++) {
        int n = bm + ty * 4 + i;
        if (n < N_NODES) {
            float4 o4 = make_float4(acc[i][0] + bv.x, acc[i][1] + bv.y,
                                    acc[i][2] + bv.z, acc[i][3] + bv.w);
            *(float4*)&out[n * 32 + tx * 4] = o4;
        }
    }
}

// ---------------- launch ----------------

extern "C" void kernel_launch(void* const* d_in, const int* in_sizes, int n_in,
                              void* d_out, int out_size, void* d_ws, size_t ws_size,
                              hipStream_t stream) {
    const float* x      = (const float*)d_in[0];   // [N,128]
    const float* Ws     = (const float*)d_in[1];   // [3,128,128]
    const float* a_src  = (const float*)d_in[2];   // [3,4,32]
    const float* a_dst  = (const float*)d_in[3];   // [3,4,32]
    const float* cbias  = (const float*)d_in[4];   // [3,128]
    const float* Wf     = (const float*)d_in[5];   // [32,128]
    const float* bf     = (const float*)d_in[6];   // [32]
    const int*   ei     = (const int*)d_in[7];     // [2,800000]
    float* out = (float*)d_out;

    char* p = (char*)d_ws;
    auto carve = [&](size_t bytes) {
        char* r = p;
        p += (bytes + 255) & ~(size_t)255;
        return r;
    };
    float* xA   = (float*)carve((size_t)N_NODES * F * 4);
    float* xB   = (float*)carve((size_t)N_NODES * F * 4);
    float* hbuf = (float*)carve((size_t)N_NODES * F * 4);
    float* asrc = (float*)carve((size_t)N_NODES * NHEAD * 4);
    float* adst = (float*)carve((size_t)N_NODES * NHEAD * 4);
    int* deg    = (int*)carve((size_t)N_NODES * 4);
    int* rowptr = (int*)carve((size_t)(N_NODES + 1) * 4);
    int* cursor = (int*)carve((size_t)N_NODES * 4);
    int* bsum   = (int*)carve((size_t)SCAN_B * 4);
    int* col    = (int*)carve((size_t)ETOT * 4);

    // ---- CSR build (dst-sorted adjacency) ----
    k_zero<<<(N_NODES + 255) / 256, 256, 0, stream>>>(deg, N_NODES);
    k_deg<<<(ETOT + 255) / 256, 256, 0, stream>>>(ei, deg);
    k_scan1<<<NBLK, SCAN_B, 0, stream>>>(deg, bsum);
    k_scan2<<<1, SCAN_B, 0, stream>>>(bsum);
    k_scan3<<<NBLK, SCAN_B, 0, stream>>>(deg, bsum, rowptr, cursor);
    k_fill<<<(ETOT + 255) / 256, 256, 0, stream>>>(ei, cursor, col);

    // ---- 3 GAT layers ----
    const float* xin = x;
    float* bufs[2] = {xA, xB};
    for (int l = 0; l < 3; l++) {
        k_gemm<<<(N_NODES + GM - 1) / GM, 256, 0, stream>>>(
            xin, Ws + (size_t)l * F * F, a_src + l * F, a_dst + l * F,
            hbuf, asrc, adst);
        k_aggr<<<(N_NODES + 3) / 4, 256, 0, stream>>>(hbuf, asrc, adst, rowptr, col,
                                                      cbias + l * F, bufs[l & 1]);
        xin = bufs[l & 1];
    }

    // ---- final linear ----
    k_fc<<<(N_NODES + FCB - 1) / FCB, 256, 0, stream>>>(xin, Wf, bf, out);
}

// Round 7
// 444.304 us; speedup vs baseline: 2.7014x; 1.1154x over previous
//
#include <hip/hip_runtime.h>
#include <hip/hip_bf16.h>
#include <math.h>

#define N_NODES 50000
#define NE      800000
#define ETOT    (NE + N_NODES)   // edges + self loops = 850000
#define F       128              // F_in == H*C
#define NHEAD   4
#define NEG     0.2f

#define SCAN_B 256
#define NBLK   ((N_NODES + SCAN_B - 1) / SCAN_B)   // 196

typedef __attribute__((ext_vector_type(8))) short bf16x8;
typedef __attribute__((ext_vector_type(4))) float f32x4;
typedef _Float16 f16x2 __attribute__((ext_vector_type(2)));

// ---------------- CSR build ----------------

__global__ void k_zero(int* __restrict__ p, int n) {
    int i = blockIdx.x * blockDim.x + threadIdx.x;
    if (i < n) p[i] = 0;
}

__global__ void k_deg(const int* __restrict__ ei, int* __restrict__ deg) {
    int i = blockIdx.x * blockDim.x + threadIdx.x;
    if (i < ETOT) {
        int d = (i < NE) ? ei[NE + i] : (i - NE);
        atomicAdd(&deg[d], 1);
    }
}

__global__ void k_scan1(const int* __restrict__ deg, int* __restrict__ bsum) {
    __shared__ int sm[SCAN_B];
    int i = blockIdx.x * SCAN_B + threadIdx.x;
    sm[threadIdx.x] = (i < N_NODES) ? deg[i] : 0;
    __syncthreads();
    for (int s = SCAN_B / 2; s > 0; s >>= 1) {
        if (threadIdx.x < s) sm[threadIdx.x] += sm[threadIdx.x + s];
        __syncthreads();
    }
    if (threadIdx.x == 0) bsum[blockIdx.x] = sm[0];
}

__global__ void k_scan2(int* __restrict__ bsum) {
    __shared__ int sm[SCAN_B];
    int t = threadIdx.x;
    int v = (t < NBLK) ? bsum[t] : 0;
    sm[t] = v; __syncthreads();
    for (int s = 1; s < SCAN_B; s <<= 1) {
        int a = (t >= s) ? sm[t - s] : 0;
        __syncthreads();
        sm[t] += a;
        __syncthreads();
    }
    if (t < NBLK) bsum[t] = sm[t] - v;  // exclusive
}

__global__ void k_scan3(const int* __restrict__ deg, const int* __restrict__ bsum,
                        int* __restrict__ rowptr, int* __restrict__ cursor) {
    __shared__ int sm[SCAN_B];
    int t = threadIdx.x;
    int i = blockIdx.x * SCAN_B + t;
    int v = (i < N_NODES) ? deg[i] : 0;
    sm[t] = v; __syncthreads();
    for (int s = 1; s < SCAN_B; s <<= 1) {
        int a = (t >= s) ? sm[t - s] : 0;
        __syncthreads();
        sm[t] += a;
        __syncthreads();
    }
    int excl = sm[t] - v + bsum[blockIdx.x];
    if (i < N_NODES) { rowptr[i] = excl; cursor[i] = excl; }
    if (i == N_NODES - 1) rowptr[N_NODES] = excl + v;
}

__global__ void k_fill(const int* __restrict__ ei, int* __restrict__ cursor,
                       int* __restrict__ col) {
    int i = blockIdx.x * blockDim.x + threadIdx.x;
    if (i < ETOT) {
        int s, d;
        if (i < NE) { s = ei[i]; d = ei[NE + i]; }
        else        { s = i - NE; d = s; }
        int pos = atomicAdd(&cursor[d], 1);
        col[pos] = s;
    }
}

// ---------------- split-bf16 helpers ----------------

__device__ __forceinline__ unsigned short f2bf(float x) {   // RNE truncate
    unsigned int u = __float_as_uint(x);
    u += 0x7FFFu + ((u >> 16) & 1u);
    return (unsigned short)(u >> 16);
}
__device__ __forceinline__ float bf2f(unsigned short h) {
    return __uint_as_float(((unsigned int)h) << 16);
}
__device__ __forceinline__ void cvt8(float4 a, float4 b, bf16x8* hi, bf16x8* lo) {
    float f[8] = {a.x, a.y, a.z, a.w, b.x, b.y, b.z, b.w};
    bf16x8 h, l;
#pragma unroll
    for (int j = 0; j < 8; j++) {
        unsigned short hu = f2bf(f[j]);
        h[j] = (short)hu;
        l[j] = (short)f2bf(f[j] - bf2f(hu));
    }
    *hi = h; *lo = l;
}

// ---------------- GEMM via split-bf16 MFMA + fused alpha ----------------
// h = X @ W^T. 64 nodes/block, 4 waves; wave w owns rows w*16..w*16+15, all
// 128 outputs (8 n-tiles). A*B ~= Ah*Bh + Ah*Bl + Al*Bh (3 MFMAs / k-tile).
// LDS 16B-unit XOR swizzle: unit(m,q) = 4m + (q ^ ((m>>1)&3)) -> <=2-way (free).
// h is stored FP16 (rel err 2^-11) to halve the k_aggr gather traffic — the
// gather is bytes-bound on the L2-miss path (round-6: 435 MB/layer, 5.7 TB/s).
// Plain launch_bounds (round-3 lesson: 2nd arg forces spills).

#define GM 64

__device__ __forceinline__ int lds_unit(int m, int q) {
    return 4 * m + (q ^ ((m >> 1) & 3));
}

__global__ __launch_bounds__(256) void k_gemm(const float* __restrict__ X,
                                              const float* __restrict__ W,
                                              const float* __restrict__ a_s,
                                              const float* __restrict__ a_d,
                                              _Float16* __restrict__ hout,
                                              float* __restrict__ asrc,
                                              float* __restrict__ adst) {
    __shared__ short Ah[256 * 8], Al[256 * 8];    // 64 rows x 4 units, 4KB each
    __shared__ short Bh[512 * 8], Bl[512 * 8];    // 128 rows x 4 units, 8KB each
    int tid = threadIdx.x;
    int bm = blockIdx.x * GM;

    // staging coords: X unit = (row am, quad aq); W units tid and tid+256
    int am = tid >> 2, aq = tid & 3;
    int xunit = ((am >> 4) << 6) + lds_unit(am & 15, aq);
    int wj = tid >> 2, wq = tid & 3;
    int wunit = ((wj >> 4) << 6) + lds_unit(wj & 15, wq);   // second = wunit+256

    // fragment coords
    int lane = tid & 63, wv = tid >> 6;
    int fm = lane & 15, fq = lane >> 4;
    int a_unit = (wv << 6) + lds_unit(fm, fq);
    int b_unit0 = lds_unit(fm, fq);

    f32x4 acc[8];
#pragma unroll
    for (int nt = 0; nt < 8; nt++) acc[nt] = (f32x4){0.f, 0.f, 0.f, 0.f};

    float4 xp0, xp1, wp0, wp1, wp2, wp3;
    int gr = bm + am;
    bool xok = (gr < N_NODES);
    const float* xrow = X + (size_t)gr * F + aq * 8;
    const float* wrow1 = W + (size_t)wj * F + wq * 8;
    const float* wrow2 = W + (size_t)(wj + 64) * F + wq * 8;
    float4 z4 = make_float4(0.f, 0.f, 0.f, 0.f);

    auto load_tile = [&](int k0) {
        xp0 = xok ? *(const float4*)(xrow + k0)     : z4;
        xp1 = xok ? *(const float4*)(xrow + k0 + 4) : z4;
        wp0 = *(const float4*)(wrow1 + k0);
        wp1 = *(const float4*)(wrow1 + k0 + 4);
        wp2 = *(const float4*)(wrow2 + k0);
        wp3 = *(const float4*)(wrow2 + k0 + 4);
    };
    auto store_tile = [&]() {
        bf16x8 hi, lo;
        cvt8(xp0, xp1, &hi, &lo);
        *(bf16x8*)&Ah[xunit * 8] = hi;  *(bf16x8*)&Al[xunit * 8] = lo;
        cvt8(wp0, wp1, &hi, &lo);
        *(bf16x8*)&Bh[wunit * 8] = hi;  *(bf16x8*)&Bl[wunit * 8] = lo;
        cvt8(wp2, wp3, &hi, &lo);
        *(bf16x8*)&Bh[(wunit + 256) * 8] = hi;  *(bf16x8*)&Bl[(wunit + 256) * 8] = lo;
    };

    load_tile(0);
    store_tile();
    __syncthreads();

#pragma unroll
    for (int t = 0; t < 4; t++) {
        if (t < 3) load_tile((t + 1) * 32);     // prefetch overlaps compute
        bf16x8 ah = *(bf16x8*)&Ah[a_unit * 8];
        bf16x8 al = *(bf16x8*)&Al[a_unit * 8];
#pragma unroll
        for (int nt = 0; nt < 8; nt++) {
            int bu = ((nt << 6) + b_unit0) * 8;
            bf16x8 bh = *(bf16x8*)&Bh[bu];
            bf16x8 bl = *(bf16x8*)&Bl[bu];
            acc[nt] = __builtin_amdgcn_mfma_f32_16x16x32_bf16(ah, bh, acc[nt], 0, 0, 0);
            acc[nt] = __builtin_amdgcn_mfma_f32_16x16x32_bf16(ah, bl, acc[nt], 0, 0, 0);
            acc[nt] = __builtin_amdgcn_mfma_f32_16x16x32_bf16(al, bh, acc[nt], 0, 0, 0);
        }
        __syncthreads();
        if (t < 3) { store_tile(); __syncthreads(); }
    }

    // epilogue: store h (fp16) + fused per-node attention logits (fp32-exact)
    float as_v[8], ad_v[8];
#pragma unroll
    for (int nt = 0; nt < 8; nt++) {
        as_v[nt] = a_s[nt * 16 + fm];
        ad_v[nt] = a_d[nt * 16 + fm];
    }
#pragma unroll
    for (int r = 0; r < 4; r++) {
        int n = bm + wv * 16 + fq * 4 + r;
        bool ok = (n < N_NODES);
        if (ok) {
#pragma unroll
            for (int nt = 0; nt < 8; nt++)
                hout[(size_t)n * F + nt * 16 + fm] = (_Float16)acc[nt][r];
        }
        float ps[4], pd[4];
#pragma unroll
        for (int hh = 0; hh < 4; hh++) {
            ps[hh] = acc[2 * hh][r] * as_v[2 * hh] + acc[2 * hh + 1][r] * as_v[2 * hh + 1];
            pd[hh] = acc[2 * hh][r] * ad_v[2 * hh] + acc[2 * hh + 1][r] * ad_v[2 * hh + 1];
        }
#pragma unroll
        for (int s = 1; s < 16; s <<= 1) {
#pragma unroll
            for (int hh = 0; hh < 4; hh++) {
                ps[hh] += __shfl_xor(ps[hh], s);
                pd[hh] += __shfl_xor(pd[hh], s);
            }
        }
        if (ok && fm == 0) {
            *(float4*)&asrc[n * 4] = make_float4(ps[0], ps[1], ps[2], ps[3]);
            *(float4*)&adst[n * 4] = make_float4(pd[0], pd[1], pd[2], pd[3]);
        }
    }
}

// ---------------- fused softmax + aggregate, one wave per dst node ----------------

__device__ __forceinline__ float selh(float4 v, int h) {
    float r = v.x;
    r = (h == 1) ? v.y : r;
    r = (h == 2) ? v.z : r;
    r = (h == 3) ? v.w : r;
    return r;
}

__global__ __launch_bounds__(256) void k_aggr(const _Float16* __restrict__ h,
                                              const float* __restrict__ asrc,
                                              const float* __restrict__ adst,
                                              const int* __restrict__ rowptr,
                                              const int* __restrict__ col,
                                              const float* __restrict__ bias,
                                              float* __restrict__ xout) {
    __shared__ int   scol[4][64];
    __shared__ float sw[4][64 * 4];
    int wave = threadIdx.x >> 6;
    int lane = threadIdx.x & 63;
    int n = blockIdx.x * 4 + wave;
    if (n >= N_NODES) return;
    int head = lane >> 4;                // lane owns channels 2*lane, 2*lane+1
    int beg = rowptr[n], end = rowptr[n + 1];
    float4 ad4 = *(const float4*)&adst[n * 4];

    float4 m4 = make_float4(-1e30f, -1e30f, -1e30f, -1e30f);
    float4 s4 = make_float4(0.f, 0.f, 0.f, 0.f);
    float accx = 0.f, accy = 0.f;

    for (int base = beg; base < end; base += 64) {
        int cnt = end - base; if (cnt > 64) cnt = 64;
        int sidx = 0;
        float4 e4 = make_float4(-1e30f, -1e30f, -1e30f, -1e30f);
        if (lane < cnt) {
            sidx = col[base + lane];
            float4 av = *(const float4*)&asrc[sidx * 4];
            float ex = av.x + ad4.x, ey = av.y + ad4.y,
                  ez = av.z + ad4.z, ew = av.w + ad4.w;
            e4.x = (ex > 0.f) ? ex : NEG * ex;
            e4.y = (ey > 0.f) ? ey : NEG * ey;
            e4.z = (ez > 0.f) ? ez : NEG * ez;
            e4.w = (ew > 0.f) ? ew : NEG * ew;
        }
        scol[wave][lane] = sidx;
        float4 M4 = e4;
#pragma unroll
        for (int s = 1; s < 64; s <<= 1) {
            M4.x = fmaxf(M4.x, __shfl_xor(M4.x, s));
            M4.y = fmaxf(M4.y, __shfl_xor(M4.y, s));
            M4.z = fmaxf(M4.z, __shfl_xor(M4.z, s));
            M4.w = fmaxf(M4.w, __shfl_xor(M4.w, s));
        }
        float4 nm;
        nm.x = fmaxf(m4.x, M4.x); nm.y = fmaxf(m4.y, M4.y);
        nm.z = fmaxf(m4.z, M4.z); nm.w = fmaxf(m4.w, M4.w);
        float4 sc;
        sc.x = __expf(m4.x - nm.x); sc.y = __expf(m4.y - nm.y);
        sc.z = __expf(m4.z - nm.z); sc.w = __expf(m4.w - nm.w);
        s4.x *= sc.x; s4.y *= sc.y; s4.z *= sc.z; s4.w *= sc.w;
        float rs = selh(sc, head);
        accx *= rs; accy *= rs;
        float4 w4;
        w4.x = (lane < cnt) ? __expf(e4.x - nm.x) : 0.f;
        w4.y = (lane < cnt) ? __expf(e4.y - nm.y) : 0.f;
        w4.z = (lane < cnt) ? __expf(e4.z - nm.z) : 0.f;
        w4.w = (lane < cnt) ? __expf(e4.w - nm.w) : 0.f;
        *(float4*)&sw[wave][lane * 4] = w4;
        float4 S4 = w4;
#pragma unroll
        for (int s = 1; s < 64; s <<= 1) {
            S4.x += __shfl_xor(S4.x, s);
            S4.y += __shfl_xor(S4.y, s);
            S4.z += __shfl_xor(S4.z, s);
            S4.w += __shfl_xor(S4.w, s);
        }
        s4.x += S4.x; s4.y += S4.y; s4.z += S4.z; s4.w += S4.w;
        m4 = nm;
        // pipelined fp16 feature gather (4B/lane); unroll 8 for MLP
#pragma unroll 8
        for (int p = 0; p < cnt; p++) {
            int s = scol[wave][p];
            float wgt = sw[wave][p * 4 + head];
            f16x2 hv = *(const f16x2*)&h[(size_t)s * F + lane * 2];
            accx = fmaf(wgt, (float)hv[0], accx);
            accy = fmaf(wgt, (float)hv[1], accy);
        }
    }

    float ssum = selh(s4, head);
    float inv = 1.f / (ssum + 1e-16f);
    float2 b2 = *(const float2*)&bias[lane * 2];
    float ox = fmaxf(fmaf(accx, inv, b2.x), 0.f);
    float oy = fmaxf(fmaf(accy, inv, b2.y), 0.f);
    *(float2*)&xout[(size_t)n * F + lane * 2] = make_float2(ox, oy);
}

// ---------------- final linear 128 -> 32: register-blocked GEMM ----------------

#define FCB 128

__global__ __launch_bounds__(256) void k_fc(const float* __restrict__ X,
                                            const float* __restrict__ Wf,
                                            const float* __restrict__ bf,
                                            float* __restrict__ out) {
    __shared__ float WsT[128 * 36];   // [k][o], staged once
    __shared__ float XsT[32 * 132];   // [k][n] per 32-k chunk
    int tid = threadIdx.x;
    int bm = blockIdx.x * FCB;

#pragma unroll
    for (int u = 0; u < 16; u++) {
        int idx = tid + 256 * u;          // 0..4095
        int o = idx >> 7, k = idx & 127;
        WsT[k * 36 + o] = Wf[idx];
    }

    int tx = tid & 7;      // outputs tx*4 .. tx*4+3
    int ty = tid >> 3;     // nodes ty*4 .. ty*4+3
    float acc[4][4];
#pragma unroll
    for (int i = 0; i < 4; i++)
#pragma unroll
        for (int j = 0; j < 4; j++) acc[i][j] = 0.f;

    for (int k0 = 0; k0 < 128; k0 += 32) {
        __syncthreads();
#pragma unroll
        for (int u = 0; u < 4; u++) {
            int f4 = tid + 256 * u;       // 0..1023 = 128 nodes x 8 float4
            int r = f4 >> 3, c4 = f4 & 7;
            int n = bm + r;
            float4 v = make_float4(0.f, 0.f, 0.f, 0.f);
            if (n < N_NODES) v = *(const float4*)&X[(size_t)n * F + k0 + c4 * 4];
            XsT[(c4 * 4 + 0) * 132 + r] = v.x;
            XsT[(c4 * 4 + 1) * 132 + r] = v.y;
            XsT[(c4 * 4 + 2) * 132 + r] = v.z;
            XsT[(c4 * 4 + 3) * 132 + r] = v.w;
        }
        __syncthreads();

#pragma unroll
        for (int kk = 0; kk < 32; kk++) {
            float4 xv = *(float4*)&XsT[kk * 132 + ty * 4];
            float4 wv = *(float4*)&WsT[(k0 + kk) * 36 + tx * 4];
            float xs[4] = {xv.x, xv.y, xv.z, xv.w};
            float ws[4] = {wv.x, wv.y, wv.z, wv.w};
#pragma unroll
            for (int i = 0; i < 4; i++)
#pragma unroll
                for (int j = 0; j < 4; j++)
                    acc[i][j] = fmaf(xs[i], ws[j], acc[i][j]);
        }
    }

    float4 bv = *(const float4*)&bf[tx * 4];
#pragma unroll
    for (int i = 0; i < 4; i++) {
        int n = bm + ty * 4 + i;
        if (n < N_NODES) {
            float4 o4 = make_float4(acc[i][0] + bv.x, acc[i][1] + bv.y,
                                    acc[i][2] + bv.z, acc[i][3] + bv.w);
            *(float4*)&out[n * 32 + tx * 4] = o4;
        }
    }
}

// ---------------- launch ----------------

extern "C" void kernel_launch(void* const* d_in, const int* in_sizes, int n_in,
                              void* d_out, int out_size, void* d_ws, size_t ws_size,
                              hipStream_t stream) {
    const float* x      = (const float*)d_in[0];   // [N,128]
    const float* Ws     = (const float*)d_in[1];   // [3,128,128]
    const float* a_src  = (const float*)d_in[2];   // [3,4,32]
    const float* a_dst  = (const float*)d_in[3];   // [3,4,32]
    const float* cbias  = (const float*)d_in[4];   // [3,128]
    const float* Wf     = (const float*)d_in[5];   // [32,128]
    const float* bf     = (const float*)d_in[6];   // [32]
    const int*   ei     = (const int*)d_in[7];     // [2,800000]
    float* out = (float*)d_out;

    char* p = (char*)d_ws;
    auto carve = [&](size_t bytes) {
        char* r = p;
        p += (bytes + 255) & ~(size_t)255;
        return r;
    };
    float* xA   = (float*)carve((size_t)N_NODES * F * 4);
    float* xB   = (float*)carve((size_t)N_NODES * F * 4);
    _Float16* hbuf = (_Float16*)carve((size_t)N_NODES * F * 2);
    float* asrc = (float*)carve((size_t)N_NODES * NHEAD * 4);
    float* adst = (float*)carve((size_t)N_NODES * NHEAD * 4);
    int* deg    = (int*)carve((size_t)N_NODES * 4);
    int* rowptr = (int*)carve((size_t)(N_NODES + 1) * 4);
    int* cursor = (int*)carve((size_t)N_NODES * 4);
    int* bsum   = (int*)carve((size_t)SCAN_B * 4);
    int* col    = (int*)carve((size_t)ETOT * 4);

    // ---- CSR build (dst-sorted adjacency) ----
    k_zero<<<(N_NODES + 255) / 256, 256, 0, stream>>>(deg, N_NODES);
    k_deg<<<(ETOT + 255) / 256, 256, 0, stream>>>(ei, deg);
    k_scan1<<<NBLK, SCAN_B, 0, stream>>>(deg, bsum);
    k_scan2<<<1, SCAN_B, 0, stream>>>(bsum);
    k_scan3<<<NBLK, SCAN_B, 0, stream>>>(deg, bsum, rowptr, cursor);
    k_fill<<<(ETOT + 255) / 256, 256, 0, stream>>>(ei, cursor, col);

    // ---- 3 GAT layers ----
    const float* xin = x;
    float* bufs[2] = {xA, xB};
    for (int l = 0; l < 3; l++) {
        k_gemm<<<(N_NODES + GM - 1) / GM, 256, 0, stream>>>(
            xin, Ws + (size_t)l * F * F, a_src + l * F, a_dst + l * F,
            hbuf, asrc, adst);
        k_aggr<<<(N_NODES + 3) / 4, 256, 0, stream>>>(hbuf, asrc, adst, rowptr, col,
                                                      cbias + l * F, bufs[l & 1]);
        xin = bufs[l & 1];
    }

    // ---- final linear ----
    k_fc<<<(N_NODES + FCB - 1) / FCB, 256, 0, stream>>>(xin, Wf, bf, out);
}

// Round 8
// 408.282 us; speedup vs baseline: 2.9397x; 1.0882x over previous
//
#include <hip/hip_runtime.h>
#include <hip/hip_bf16.h>
#include <math.h>

#define N_NODES 50000
#define NE      800000
#define ETOT    (NE + N_NODES)   // edges + self loops = 850000
#define F       128              // F_in == H*C
#define NHEAD   4
#define NEG     0.2f

#define SCAN_B 256
#define NBLK   ((N_NODES + SCAN_B - 1) / SCAN_B)   // 196

typedef __attribute__((ext_vector_type(8))) short bf16x8;
typedef __attribute__((ext_vector_type(4))) float f32x4;
typedef _Float16 f16x2 __attribute__((ext_vector_type(2)));
typedef _Float16 f16x4 __attribute__((ext_vector_type(4)));

// ---------------- CSR build ----------------

__global__ void k_zero(int* __restrict__ p, int n) {
    int i = blockIdx.x * blockDim.x + threadIdx.x;
    if (i < n) p[i] = 0;
}

__global__ void k_deg(const int* __restrict__ ei, int* __restrict__ deg) {
    int i = blockIdx.x * blockDim.x + threadIdx.x;
    if (i < ETOT) {
        int d = (i < NE) ? ei[NE + i] : (i - NE);
        atomicAdd(&deg[d], 1);
    }
}

__global__ void k_scan1(const int* __restrict__ deg, int* __restrict__ bsum) {
    __shared__ int sm[SCAN_B];
    int i = blockIdx.x * SCAN_B + threadIdx.x;
    sm[threadIdx.x] = (i < N_NODES) ? deg[i] : 0;
    __syncthreads();
    for (int s = SCAN_B / 2; s > 0; s >>= 1) {
        if (threadIdx.x < s) sm[threadIdx.x] += sm[threadIdx.x + s];
        __syncthreads();
    }
    if (threadIdx.x == 0) bsum[blockIdx.x] = sm[0];
}

__global__ void k_scan2(int* __restrict__ bsum) {
    __shared__ int sm[SCAN_B];
    int t = threadIdx.x;
    int v = (t < NBLK) ? bsum[t] : 0;
    sm[t] = v; __syncthreads();
    for (int s = 1; s < SCAN_B; s <<= 1) {
        int a = (t >= s) ? sm[t - s] : 0;
        __syncthreads();
        sm[t] += a;
        __syncthreads();
    }
    if (t < NBLK) bsum[t] = sm[t] - v;  // exclusive
}

__global__ void k_scan3(const int* __restrict__ deg, const int* __restrict__ bsum,
                        int* __restrict__ rowptr, int* __restrict__ cursor) {
    __shared__ int sm[SCAN_B];
    int t = threadIdx.x;
    int i = blockIdx.x * SCAN_B + t;
    int v = (i < N_NODES) ? deg[i] : 0;
    sm[t] = v; __syncthreads();
    for (int s = 1; s < SCAN_B; s <<= 1) {
        int a = (t >= s) ? sm[t - s] : 0;
        __syncthreads();
        sm[t] += a;
        __syncthreads();
    }
    int excl = sm[t] - v + bsum[blockIdx.x];
    if (i < N_NODES) { rowptr[i] = excl; cursor[i] = excl; }
    if (i == N_NODES - 1) rowptr[N_NODES] = excl + v;
}

__global__ void k_fill(const int* __restrict__ ei, int* __restrict__ cursor,
                       int* __restrict__ col) {
    int i = blockIdx.x * blockDim.x + threadIdx.x;
    if (i < ETOT) {
        int s, d;
        if (i < NE) { s = ei[i]; d = ei[NE + i]; }
        else        { s = i - NE; d = s; }
        int pos = atomicAdd(&cursor[d], 1);
        col[pos] = s;
    }
}

// ---------------- split-bf16 helpers ----------------

__device__ __forceinline__ unsigned short f2bf(float x) {   // RNE truncate
    unsigned int u = __float_as_uint(x);
    u += 0x7FFFu + ((u >> 16) & 1u);
    return (unsigned short)(u >> 16);
}
__device__ __forceinline__ float bf2f(unsigned short h) {
    return __uint_as_float(((unsigned int)h) << 16);
}
__device__ __forceinline__ void cvt8(float4 a, float4 b, bf16x8* hi, bf16x8* lo) {
    float f[8] = {a.x, a.y, a.z, a.w, b.x, b.y, b.z, b.w};
    bf16x8 h, l;
#pragma unroll
    for (int j = 0; j < 8; j++) {
        unsigned short hu = f2bf(f[j]);
        h[j] = (short)hu;
        l[j] = (short)f2bf(f[j] - bf2f(hu));
    }
    *hi = h; *lo = l;
}

// ---------------- GEMM via split-bf16 MFMA + fused alpha ----------------
// h = X @ W^T. 64 nodes/block, 4 waves; wave w owns rows w*16..w*16+15, all
// 128 outputs (8 n-tiles). A*B ~= Ah*Bh + Ah*Bl + Al*Bh (3 MFMAs / k-tile).
// LDS 16B-unit XOR swizzle: unit(m,q) = 4m + (q ^ ((m>>1)&3)) -> <=2-way (free).
// h is stored FP16 (rel err 2^-11): halves the k_aggr gather traffic.
// Plain launch_bounds (round-3 lesson: 2nd arg forces spills).

#define GM 64

__device__ __forceinline__ int lds_unit(int m, int q) {
    return 4 * m + (q ^ ((m >> 1) & 3));
}

__global__ __launch_bounds__(256) void k_gemm(const float* __restrict__ X,
                                              const float* __restrict__ W,
                                              const float* __restrict__ a_s,
                                              const float* __restrict__ a_d,
                                              _Float16* __restrict__ hout,
                                              float* __restrict__ asrc,
                                              float* __restrict__ adst) {
    __shared__ short Ah[256 * 8], Al[256 * 8];    // 64 rows x 4 units, 4KB each
    __shared__ short Bh[512 * 8], Bl[512 * 8];    // 128 rows x 4 units, 8KB each
    int tid = threadIdx.x;
    int bm = blockIdx.x * GM;

    // staging coords: X unit = (row am, quad aq); W units tid and tid+256
    int am = tid >> 2, aq = tid & 3;
    int xunit = ((am >> 4) << 6) + lds_unit(am & 15, aq);
    int wj = tid >> 2, wq = tid & 3;
    int wunit = ((wj >> 4) << 6) + lds_unit(wj & 15, wq);   // second = wunit+256

    // fragment coords
    int lane = tid & 63, wv = tid >> 6;
    int fm = lane & 15, fq = lane >> 4;
    int a_unit = (wv << 6) + lds_unit(fm, fq);
    int b_unit0 = lds_unit(fm, fq);

    f32x4 acc[8];
#pragma unroll
    for (int nt = 0; nt < 8; nt++) acc[nt] = (f32x4){0.f, 0.f, 0.f, 0.f};

    float4 xp0, xp1, wp0, wp1, wp2, wp3;
    int gr = bm + am;
    bool xok = (gr < N_NODES);
    const float* xrow = X + (size_t)gr * F + aq * 8;
    const float* wrow1 = W + (size_t)wj * F + wq * 8;
    const float* wrow2 = W + (size_t)(wj + 64) * F + wq * 8;
    float4 z4 = make_float4(0.f, 0.f, 0.f, 0.f);

    auto load_tile = [&](int k0) {
        xp0 = xok ? *(const float4*)(xrow + k0)     : z4;
        xp1 = xok ? *(const float4*)(xrow + k0 + 4) : z4;
        wp0 = *(const float4*)(wrow1 + k0);
        wp1 = *(const float4*)(wrow1 + k0 + 4);
        wp2 = *(const float4*)(wrow2 + k0);
        wp3 = *(const float4*)(wrow2 + k0 + 4);
    };
    auto store_tile = [&]() {
        bf16x8 hi, lo;
        cvt8(xp0, xp1, &hi, &lo);
        *(bf16x8*)&Ah[xunit * 8] = hi;  *(bf16x8*)&Al[xunit * 8] = lo;
        cvt8(wp0, wp1, &hi, &lo);
        *(bf16x8*)&Bh[wunit * 8] = hi;  *(bf16x8*)&Bl[wunit * 8] = lo;
        cvt8(wp2, wp3, &hi, &lo);
        *(bf16x8*)&Bh[(wunit + 256) * 8] = hi;  *(bf16x8*)&Bl[(wunit + 256) * 8] = lo;
    };

    load_tile(0);
    store_tile();
    __syncthreads();

#pragma unroll
    for (int t = 0; t < 4; t++) {
        if (t < 3) load_tile((t + 1) * 32);     // prefetch overlaps compute
        bf16x8 ah = *(bf16x8*)&Ah[a_unit * 8];
        bf16x8 al = *(bf16x8*)&Al[a_unit * 8];
#pragma unroll
        for (int nt = 0; nt < 8; nt++) {
            int bu = ((nt << 6) + b_unit0) * 8;
            bf16x8 bh = *(bf16x8*)&Bh[bu];
            bf16x8 bl = *(bf16x8*)&Bl[bu];
            acc[nt] = __builtin_amdgcn_mfma_f32_16x16x32_bf16(ah, bh, acc[nt], 0, 0, 0);
            acc[nt] = __builtin_amdgcn_mfma_f32_16x16x32_bf16(ah, bl, acc[nt], 0, 0, 0);
            acc[nt] = __builtin_amdgcn_mfma_f32_16x16x32_bf16(al, bh, acc[nt], 0, 0, 0);
        }
        __syncthreads();
        if (t < 3) { store_tile(); __syncthreads(); }
    }

    // epilogue: store h (fp16) + fused per-node attention logits (fp32-exact)
    float as_v[8], ad_v[8];
#pragma unroll
    for (int nt = 0; nt < 8; nt++) {
        as_v[nt] = a_s[nt * 16 + fm];
        ad_v[nt] = a_d[nt * 16 + fm];
    }
#pragma unroll
    for (int r = 0; r < 4; r++) {
        int n = bm + wv * 16 + fq * 4 + r;
        bool ok = (n < N_NODES);
        if (ok) {
#pragma unroll
            for (int nt = 0; nt < 8; nt++)
                hout[(size_t)n * F + nt * 16 + fm] = (_Float16)acc[nt][r];
        }
        float ps[4], pd[4];
#pragma unroll
        for (int hh = 0; hh < 4; hh++) {
            ps[hh] = acc[2 * hh][r] * as_v[2 * hh] + acc[2 * hh + 1][r] * as_v[2 * hh + 1];
            pd[hh] = acc[2 * hh][r] * ad_v[2 * hh] + acc[2 * hh + 1][r] * ad_v[2 * hh + 1];
        }
#pragma unroll
        for (int s = 1; s < 16; s <<= 1) {
#pragma unroll
            for (int hh = 0; hh < 4; hh++) {
                ps[hh] += __shfl_xor(ps[hh], s);
                pd[hh] += __shfl_xor(pd[hh], s);
            }
        }
        if (ok && fm == 0) {
            *(float4*)&asrc[n * 4] = make_float4(ps[0], ps[1], ps[2], ps[3]);
            *(float4*)&adst[n * 4] = make_float4(pd[0], pd[1], pd[2], pd[3]);
        }
    }
}

// ---------------- fused softmax + aggregate, one wave per dst node ----------------
// Gather processes 2 edges/wave-instruction: lane half hl handles edge p+hl,
// 32 lanes cover the 256B fp16 row via f16x4 (8B/lane). Halves combined at the
// end with shfl_xor(32). First chunk skips the online-rescale block (deg<=64
// for essentially every node -> rescale never executes).

__device__ __forceinline__ float selh(float4 v, int h) {
    float r = v.x;
    r = (h == 1) ? v.y : r;
    r = (h == 2) ? v.z : r;
    r = (h == 3) ? v.w : r;
    return r;
}

__global__ __launch_bounds__(256) void k_aggr(const _Float16* __restrict__ h,
                                              const float* __restrict__ asrc,
                                              const float* __restrict__ adst,
                                              const int* __restrict__ rowptr,
                                              const int* __restrict__ col,
                                              const float* __restrict__ bias,
                                              float* __restrict__ xout) {
    __shared__ int   scol[4][64];
    __shared__ float sw[4][64 * 4];
    int wave = threadIdx.x >> 6;
    int lane = threadIdx.x & 63;
    int n = blockIdx.x * 4 + wave;
    if (n >= N_NODES) return;
    int hl = lane >> 5;            // which edge of the pair
    int wl = lane & 31;            // channels wl*4 .. wl*4+3
    int whead = wl >> 3;           // head of those channels
    int beg = rowptr[n], end = rowptr[n + 1];
    float4 ad4 = *(const float4*)&adst[n * 4];

    float4 m4 = make_float4(-1e30f, -1e30f, -1e30f, -1e30f);
    float4 s4 = make_float4(0.f, 0.f, 0.f, 0.f);
    float4 acc4 = make_float4(0.f, 0.f, 0.f, 0.f);

    for (int base = beg; base < end; base += 64) {
        int cnt = end - base; if (cnt > 64) cnt = 64;
        int sidx = 0;
        float4 e4 = make_float4(-1e30f, -1e30f, -1e30f, -1e30f);
        if (lane < cnt) {
            sidx = col[base + lane];
            float4 av = *(const float4*)&asrc[sidx * 4];
            float ex = av.x + ad4.x, ey = av.y + ad4.y,
                  ez = av.z + ad4.z, ew = av.w + ad4.w;
            e4.x = (ex > 0.f) ? ex : NEG * ex;
            e4.y = (ey > 0.f) ? ey : NEG * ey;
            e4.z = (ez > 0.f) ? ez : NEG * ez;
            e4.w = (ew > 0.f) ? ew : NEG * ew;
        }
        scol[wave][lane] = sidx;
        float4 M4 = e4;
#pragma unroll
        for (int s = 1; s < 64; s <<= 1) {
            M4.x = fmaxf(M4.x, __shfl_xor(M4.x, s));
            M4.y = fmaxf(M4.y, __shfl_xor(M4.y, s));
            M4.z = fmaxf(M4.z, __shfl_xor(M4.z, s));
            M4.w = fmaxf(M4.w, __shfl_xor(M4.w, s));
        }
        if (base == beg) {
            m4 = M4;               // first chunk: no rescale (acc/s are zero)
        } else {
            float4 nm;
            nm.x = fmaxf(m4.x, M4.x); nm.y = fmaxf(m4.y, M4.y);
            nm.z = fmaxf(m4.z, M4.z); nm.w = fmaxf(m4.w, M4.w);
            float4 sc;
            sc.x = __expf(m4.x - nm.x); sc.y = __expf(m4.y - nm.y);
            sc.z = __expf(m4.z - nm.z); sc.w = __expf(m4.w - nm.w);
            s4.x *= sc.x; s4.y *= sc.y; s4.z *= sc.z; s4.w *= sc.w;
            float rs = selh(sc, whead);
            acc4.x *= rs; acc4.y *= rs; acc4.z *= rs; acc4.w *= rs;
            m4 = nm;
        }
        float4 w4;
        w4.x = (lane < cnt) ? __expf(e4.x - m4.x) : 0.f;
        w4.y = (lane < cnt) ? __expf(e4.y - m4.y) : 0.f;
        w4.z = (lane < cnt) ? __expf(e4.z - m4.z) : 0.f;
        w4.w = (lane < cnt) ? __expf(e4.w - m4.w) : 0.f;
        *(float4*)&sw[wave][lane * 4] = w4;
        float4 S4 = w4;
#pragma unroll
        for (int s = 1; s < 64; s <<= 1) {
            S4.x += __shfl_xor(S4.x, s);
            S4.y += __shfl_xor(S4.y, s);
            S4.z += __shfl_xor(S4.z, s);
            S4.w += __shfl_xor(S4.w, s);
        }
        s4.x += S4.x; s4.y += S4.y; s4.z += S4.z; s4.w += S4.w;
        // paired fp16 feature gather: edge p+hl, 8B/lane, 512B/wave-instr.
        // lanes >= cnt wrote sidx=0 & w4=0, so the pad edge is a no-op.
#pragma unroll 4
        for (int p = 0; p < cnt; p += 2) {
            int s = scol[wave][p + hl];
            float wgt = sw[wave][(p + hl) * 4 + whead];
            f16x4 hv = *(const f16x4*)&h[(size_t)s * F + wl * 4];
            acc4.x = fmaf(wgt, (float)hv[0], acc4.x);
            acc4.y = fmaf(wgt, (float)hv[1], acc4.y);
            acc4.z = fmaf(wgt, (float)hv[2], acc4.z);
            acc4.w = fmaf(wgt, (float)hv[3], acc4.w);
        }
    }

    // combine edge-halves: channel c lives on lane wl in both halves
    acc4.x += __shfl_xor(acc4.x, 32);
    acc4.y += __shfl_xor(acc4.y, 32);
    acc4.z += __shfl_xor(acc4.z, 32);
    acc4.w += __shfl_xor(acc4.w, 32);

    if (hl == 0) {
        float ssum = selh(s4, whead);
        float inv = 1.f / (ssum + 1e-16f);
        float4 bv = *(const float4*)&bias[wl * 4];
        float4 o;
        o.x = fmaxf(fmaf(acc4.x, inv, bv.x), 0.f);
        o.y = fmaxf(fmaf(acc4.y, inv, bv.y), 0.f);
        o.z = fmaxf(fmaf(acc4.z, inv, bv.z), 0.f);
        o.w = fmaxf(fmaf(acc4.w, inv, bv.w), 0.f);
        *(float4*)&xout[(size_t)n * F + wl * 4] = o;
    }
}

// ---------------- final linear 128 -> 32: register-blocked GEMM ----------------

#define FCB 128

__global__ __launch_bounds__(256) void k_fc(const float* __restrict__ X,
                                            const float* __restrict__ Wf,
                                            const float* __restrict__ bf,
                                            float* __restrict__ out) {
    __shared__ float WsT[128 * 36];   // [k][o], staged once
    __shared__ float XsT[32 * 132];   // [k][n] per 32-k chunk
    int tid = threadIdx.x;
    int bm = blockIdx.x * FCB;

#pragma unroll
    for (int u = 0; u < 16; u++) {
        int idx = tid + 256 * u;          // 0..4095
        int o = idx >> 7, k = idx & 127;
        WsT[k * 36 + o] = Wf[idx];
    }

    int tx = tid & 7;      // outputs tx*4 .. tx*4+3
    int ty = tid >> 3;     // nodes ty*4 .. ty*4+3
    float acc[4][4];
#pragma unroll
    for (int i = 0; i < 4; i++)
#pragma unroll
        for (int j = 0; j < 4; j++) acc[i][j] = 0.f;

    for (int k0 = 0; k0 < 128; k0 += 32) {
        __syncthreads();
#pragma unroll
        for (int u = 0; u < 4; u++) {
            int f4 = tid + 256 * u;       // 0..1023 = 128 nodes x 8 float4
            int r = f4 >> 3, c4 = f4 & 7;
            int n = bm + r;
            float4 v = make_float4(0.f, 0.f, 0.f, 0.f);
            if (n < N_NODES) v = *(const float4*)&X[(size_t)n * F + k0 + c4 * 4];
            XsT[(c4 * 4 + 0) * 132 + r] = v.x;
            XsT[(c4 * 4 + 1) * 132 + r] = v.y;
            XsT[(c4 * 4 + 2) * 132 + r] = v.z;
            XsT[(c4 * 4 + 3) * 132 + r] = v.w;
        }
        __syncthreads();

#pragma unroll
        for (int kk = 0; kk < 32; kk++) {
            float4 xv = *(float4*)&XsT[kk * 132 + ty * 4];
            float4 wv = *(float4*)&WsT[(k0 + kk) * 36 + tx * 4];
            float xs[4] = {xv.x, xv.y, xv.z, xv.w};
            float ws[4] = {wv.x, wv.y, wv.z, wv.w};
#pragma unroll
            for (int i = 0; i < 4; i++)
#pragma unroll
                for (int j = 0; j < 4; j++)
                    acc[i][j] = fmaf(xs[i], ws[j], acc[i][j]);
        }
    }

    float4 bv = *(const float4*)&bf[tx * 4];
#pragma unroll
    for (int i = 0; i < 4; i++) {
        int n = bm + ty * 4 + i;
        if (n < N_NODES) {
            float4 o4 = make_float4(acc[i][0] + bv.x, acc[i][1] + bv.y,
                                    acc[i][2] + bv.z, acc[i][3] + bv.w);
            *(float4*)&out[n * 32 + tx * 4] = o4;
        }
    }
}

// ---------------- launch ----------------

extern "C" void kernel_launch(void* const* d_in, const int* in_sizes, int n_in,
                              void* d_out, int out_size, void* d_ws, size_t ws_size,
                              hipStream_t stream) {
    const float* x      = (const float*)d_in[0];   // [N,128]
    const float* Ws     = (const float*)d_in[1];   // [3,128,128]
    const float* a_src  = (const float*)d_in[2];   // [3,4,32]
    const float* a_dst  = (const float*)d_in[3];   // [3,4,32]
    const float* cbias  = (const float*)d_in[4];   // [3,128]
    const float* Wf     = (const float*)d_in[5];   // [32,128]
    const float* bf     = (const float*)d_in[6];   // [32]
    const int*   ei     = (const int*)d_in[7];     // [2,800000]
    float* out = (float*)d_out;

    char* p = (char*)d_ws;
    auto carve = [&](size_t bytes) {
        char* r = p;
        p += (bytes + 255) & ~(size_t)255;
        return r;
    };
    float* xA   = (float*)carve((size_t)N_NODES * F * 4);
    float* xB   = (float*)carve((size_t)N_NODES * F * 4);
    _Float16* hbuf = (_Float16*)carve((size_t)N_NODES * F * 2);
    float* asrc = (float*)carve((size_t)N_NODES * NHEAD * 4);
    float* adst = (float*)carve((size_t)N_NODES * NHEAD * 4);
    int* deg    = (int*)carve((size_t)N_NODES * 4);
    int* rowptr = (int*)carve((size_t)(N_NODES + 1) * 4);
    int* cursor = (int*)carve((size_t)N_NODES * 4);
    int* bsum   = (int*)carve((size_t)SCAN_B * 4);
    int* col    = (int*)carve((size_t)ETOT * 4);

    // ---- CSR build (dst-sorted adjacency) ----
    k_zero<<<(N_NODES + 255) / 256, 256, 0, stream>>>(deg, N_NODES);
    k_deg<<<(ETOT + 255) / 256, 256, 0, stream>>>(ei, deg);
    k_scan1<<<NBLK, SCAN_B, 0, stream>>>(deg, bsum);
    k_scan2<<<1, SCAN_B, 0, stream>>>(bsum);
    k_scan3<<<NBLK, SCAN_B, 0, stream>>>(deg, bsum, rowptr, cursor);
    k_fill<<<(ETOT + 255) / 256, 256, 0, stream>>>(ei, cursor, col);

    // ---- 3 GAT layers ----
    const float* xin = x;
    float* bufs[2] = {xA, xB};
    for (int l = 0; l < 3; l++) {
        k_gemm<<<(N_NODES + GM - 1) / GM, 256, 0, stream>>>(
            xin, Ws + (size_t)l * F * F, a_src + l * F, a_dst + l * F,
            hbuf, asrc, adst);
        k_aggr<<<(N_NODES + 3) / 4, 256, 0, stream>>>(hbuf, asrc, adst, rowptr, col,
                                                      cbias + l * F, bufs[l & 1]);
        xin = bufs[l & 1];
    }

    // ---- final linear ----
    k_fc<<<(N_NODES + FCB - 1) / FCB, 256, 0, stream>>>(xin, Wf, bf, out);
}

// Round 9
// 369.546 us; speedup vs baseline: 3.2479x; 1.1048x over previous
//
#include <hip/hip_runtime.h>
#include <hip/hip_bf16.h>
#include <math.h>

#define N_NODES 50000
#define NE      800000
#define ETOT    (NE + N_NODES)   // edges + self loops = 850000
#define F       128              // F_in == H*C
#define NHEAD   4
#define NEG     0.2f

#define SCAN_B 256
#define NBLK   ((N_NODES + SCAN_B - 1) / SCAN_B)   // 196

typedef __attribute__((ext_vector_type(8))) short bf16x8;
typedef __attribute__((ext_vector_type(4))) float f32x4;
typedef _Float16 f16x2 __attribute__((ext_vector_type(2)));
typedef _Float16 f16x4 __attribute__((ext_vector_type(4)));
typedef _Float16 f16x8 __attribute__((ext_vector_type(8)));

// ---------------- CSR build ----------------
// Round-9: k_deg records each edge's intra-dst rank (the atomicAdd return);
// k_fill becomes atomic-free: pos = rowptr[d] + rank[i]. The 850k random
// L2 atomics in the old k_fill were its 55us (VALUBusy 0.46%).

__global__ void k_zero(int* __restrict__ p, int n) {
    int i = blockIdx.x * blockDim.x + threadIdx.x;
    if (i < n) p[i] = 0;
}

__global__ void k_deg(const int* __restrict__ ei, int* __restrict__ deg,
                      int* __restrict__ rank) {
    int i = blockIdx.x * blockDim.x + threadIdx.x;
    if (i < ETOT) {
        int d = (i < NE) ? ei[NE + i] : (i - NE);
        rank[i] = atomicAdd(&deg[d], 1);
    }
}

__global__ void k_scan1(const int* __restrict__ deg, int* __restrict__ bsum) {
    __shared__ int sm[SCAN_B];
    int i = blockIdx.x * SCAN_B + threadIdx.x;
    sm[threadIdx.x] = (i < N_NODES) ? deg[i] : 0;
    __syncthreads();
    for (int s = SCAN_B / 2; s > 0; s >>= 1) {
        if (threadIdx.x < s) sm[threadIdx.x] += sm[threadIdx.x + s];
        __syncthreads();
    }
    if (threadIdx.x == 0) bsum[blockIdx.x] = sm[0];
}

__global__ void k_scan2(int* __restrict__ bsum) {
    __shared__ int sm[SCAN_B];
    int t = threadIdx.x;
    int v = (t < NBLK) ? bsum[t] : 0;
    sm[t] = v; __syncthreads();
    for (int s = 1; s < SCAN_B; s <<= 1) {
        int a = (t >= s) ? sm[t - s] : 0;
        __syncthreads();
        sm[t] += a;
        __syncthreads();
    }
    if (t < NBLK) bsum[t] = sm[t] - v;  // exclusive
}

__global__ void k_scan3(const int* __restrict__ deg, const int* __restrict__ bsum,
                        int* __restrict__ rowptr) {
    __shared__ int sm[SCAN_B];
    int t = threadIdx.x;
    int i = blockIdx.x * SCAN_B + t;
    int v = (i < N_NODES) ? deg[i] : 0;
    sm[t] = v; __syncthreads();
    for (int s = 1; s < SCAN_B; s <<= 1) {
        int a = (t >= s) ? sm[t - s] : 0;
        __syncthreads();
        sm[t] += a;
        __syncthreads();
    }
    int excl = sm[t] - v + bsum[blockIdx.x];
    if (i < N_NODES) rowptr[i] = excl;
    if (i == N_NODES - 1) rowptr[N_NODES] = excl + v;
}

__global__ void k_fill(const int* __restrict__ ei, const int* __restrict__ rowptr,
                       const int* __restrict__ rank, int* __restrict__ col) {
    int i = blockIdx.x * blockDim.x + threadIdx.x;
    if (i < ETOT) {
        int s, d;
        if (i < NE) { s = ei[i]; d = ei[NE + i]; }
        else        { s = i - NE; d = s; }
        col[rowptr[d] + rank[i]] = s;
    }
}

// ---------------- split-bf16 helpers ----------------

__device__ __forceinline__ unsigned short f2bf(float x) {   // RNE truncate
    unsigned int u = __float_as_uint(x);
    u += 0x7FFFu + ((u >> 16) & 1u);
    return (unsigned short)(u >> 16);
}
__device__ __forceinline__ float bf2f(unsigned short h) {
    return __uint_as_float(((unsigned int)h) << 16);
}
__device__ __forceinline__ void cvt8(float4 a, float4 b, bf16x8* hi, bf16x8* lo) {
    float f[8] = {a.x, a.y, a.z, a.w, b.x, b.y, b.z, b.w};
    bf16x8 h, l;
#pragma unroll
    for (int j = 0; j < 8; j++) {
        unsigned short hu = f2bf(f[j]);
        h[j] = (short)hu;
        l[j] = (short)f2bf(f[j] - bf2f(hu));
    }
    *hi = h; *lo = l;
}

// ---------------- GEMM via split-bf16 MFMA + fused alpha ----------------
// h = X @ W^T. 64 nodes/block, 4 waves; wave w owns rows w*16..w*16+15, all
// 128 outputs (8 n-tiles). A*B ~= Ah*Bh + Ah*Bl + Al*Bh (3 MFMAs / k-tile).
// LDS 16B-unit XOR swizzle: unit(m,q) = 4m + (q ^ ((m>>1)&3)) -> <=2-way (free).
// h is stored FP16 (rel err 2^-11): halves the k_aggr gather traffic.
// Plain launch_bounds (round-3 lesson: 2nd arg forces spills).

#define GM 64

__device__ __forceinline__ int lds_unit(int m, int q) {
    return 4 * m + (q ^ ((m >> 1) & 3));
}

__global__ __launch_bounds__(256) void k_gemm(const float* __restrict__ X,
                                              const float* __restrict__ W,
                                              const float* __restrict__ a_s,
                                              const float* __restrict__ a_d,
                                              _Float16* __restrict__ hout,
                                              float* __restrict__ asrc,
                                              float* __restrict__ adst) {
    __shared__ short Ah[256 * 8], Al[256 * 8];    // 64 rows x 4 units, 4KB each
    __shared__ short Bh[512 * 8], Bl[512 * 8];    // 128 rows x 4 units, 8KB each
    int tid = threadIdx.x;
    int bm = blockIdx.x * GM;

    // staging coords: X unit = (row am, quad aq); W units tid and tid+256
    int am = tid >> 2, aq = tid & 3;
    int xunit = ((am >> 4) << 6) + lds_unit(am & 15, aq);
    int wj = tid >> 2, wq = tid & 3;
    int wunit = ((wj >> 4) << 6) + lds_unit(wj & 15, wq);   // second = wunit+256

    // fragment coords
    int lane = tid & 63, wv = tid >> 6;
    int fm = lane & 15, fq = lane >> 4;
    int a_unit = (wv << 6) + lds_unit(fm, fq);
    int b_unit0 = lds_unit(fm, fq);

    f32x4 acc[8];
#pragma unroll
    for (int nt = 0; nt < 8; nt++) acc[nt] = (f32x4){0.f, 0.f, 0.f, 0.f};

    float4 xp0, xp1, wp0, wp1, wp2, wp3;
    int gr = bm + am;
    bool xok = (gr < N_NODES);
    const float* xrow = X + (size_t)gr * F + aq * 8;
    const float* wrow1 = W + (size_t)wj * F + wq * 8;
    const float* wrow2 = W + (size_t)(wj + 64) * F + wq * 8;
    float4 z4 = make_float4(0.f, 0.f, 0.f, 0.f);

    auto load_tile = [&](int k0) {
        xp0 = xok ? *(const float4*)(xrow + k0)     : z4;
        xp1 = xok ? *(const float4*)(xrow + k0 + 4) : z4;
        wp0 = *(const float4*)(wrow1 + k0);
        wp1 = *(const float4*)(wrow1 + k0 + 4);
        wp2 = *(const float4*)(wrow2 + k0);
        wp3 = *(const float4*)(wrow2 + k0 + 4);
    };
    auto store_tile = [&]() {
        bf16x8 hi, lo;
        cvt8(xp0, xp1, &hi, &lo);
        *(bf16x8*)&Ah[xunit * 8] = hi;  *(bf16x8*)&Al[xunit * 8] = lo;
        cvt8(wp0, wp1, &hi, &lo);
        *(bf16x8*)&Bh[wunit * 8] = hi;  *(bf16x8*)&Bl[wunit * 8] = lo;
        cvt8(wp2, wp3, &hi, &lo);
        *(bf16x8*)&Bh[(wunit + 256) * 8] = hi;  *(bf16x8*)&Bl[(wunit + 256) * 8] = lo;
    };

    load_tile(0);
    store_tile();
    __syncthreads();

#pragma unroll
    for (int t = 0; t < 4; t++) {
        if (t < 3) load_tile((t + 1) * 32);     // prefetch overlaps compute
        bf16x8 ah = *(bf16x8*)&Ah[a_unit * 8];
        bf16x8 al = *(bf16x8*)&Al[a_unit * 8];
#pragma unroll
        for (int nt = 0; nt < 8; nt++) {
            int bu = ((nt << 6) + b_unit0) * 8;
            bf16x8 bh = *(bf16x8*)&Bh[bu];
            bf16x8 bl = *(bf16x8*)&Bl[bu];
            acc[nt] = __builtin_amdgcn_mfma_f32_16x16x32_bf16(ah, bh, acc[nt], 0, 0, 0);
            acc[nt] = __builtin_amdgcn_mfma_f32_16x16x32_bf16(ah, bl, acc[nt], 0, 0, 0);
            acc[nt] = __builtin_amdgcn_mfma_f32_16x16x32_bf16(al, bh, acc[nt], 0, 0, 0);
        }
        __syncthreads();
        if (t < 3) { store_tile(); __syncthreads(); }
    }

    // epilogue: store h (fp16) + fused per-node attention logits (fp32-exact)
    float as_v[8], ad_v[8];
#pragma unroll
    for (int nt = 0; nt < 8; nt++) {
        as_v[nt] = a_s[nt * 16 + fm];
        ad_v[nt] = a_d[nt * 16 + fm];
    }
#pragma unroll
    for (int r = 0; r < 4; r++) {
        int n = bm + wv * 16 + fq * 4 + r;
        bool ok = (n < N_NODES);
        if (ok) {
#pragma unroll
            for (int nt = 0; nt < 8; nt++)
                hout[(size_t)n * F + nt * 16 + fm] = (_Float16)acc[nt][r];
        }
        float ps[4], pd[4];
#pragma unroll
        for (int hh = 0; hh < 4; hh++) {
            ps[hh] = acc[2 * hh][r] * as_v[2 * hh] + acc[2 * hh + 1][r] * as_v[2 * hh + 1];
            pd[hh] = acc[2 * hh][r] * ad_v[2 * hh] + acc[2 * hh + 1][r] * ad_v[2 * hh + 1];
        }
#pragma unroll
        for (int s = 1; s < 16; s <<= 1) {
#pragma unroll
            for (int hh = 0; hh < 4; hh++) {
                ps[hh] += __shfl_xor(ps[hh], s);
                pd[hh] += __shfl_xor(pd[hh], s);
            }
        }
        if (ok && fm == 0) {
            *(float4*)&asrc[n * 4] = make_float4(ps[0], ps[1], ps[2], ps[3]);
            *(float4*)&adst[n * 4] = make_float4(pd[0], pd[1], pd[2], pd[3]);
        }
    }
}

// ---------------- fused softmax + aggregate, one wave per dst node ----------------
// Gather: 2 edges/wave-instruction (lane half hl = edge p+hl), f16x4 8B/lane.
// First chunk skips online-rescale (deg<=64 virtually always). Output type is
// templated: layers 0,1 write fp32; layer 2 writes fp16 so k_fc reads half.

__device__ __forceinline__ float selh(float4 v, int h) {
    float r = v.x;
    r = (h == 1) ? v.y : r;
    r = (h == 2) ? v.z : r;
    r = (h == 3) ? v.w : r;
    return r;
}

template <typename OutT>
__global__ __launch_bounds__(256) void k_aggr(const _Float16* __restrict__ h,
                                              const float* __restrict__ asrc,
                                              const float* __restrict__ adst,
                                              const int* __restrict__ rowptr,
                                              const int* __restrict__ col,
                                              const float* __restrict__ bias,
                                              OutT* __restrict__ xout) {
    __shared__ int   scol[4][64];
    __shared__ float sw[4][64 * 4];
    int wave = threadIdx.x >> 6;
    int lane = threadIdx.x & 63;
    int n = blockIdx.x * 4 + wave;
    if (n >= N_NODES) return;
    int hl = lane >> 5;            // which edge of the pair
    int wl = lane & 31;            // channels wl*4 .. wl*4+3
    int whead = wl >> 3;           // head of those channels
    int beg = rowptr[n], end = rowptr[n + 1];
    float4 ad4 = *(const float4*)&adst[n * 4];

    float4 m4 = make_float4(-1e30f, -1e30f, -1e30f, -1e30f);
    float4 s4 = make_float4(0.f, 0.f, 0.f, 0.f);
    float4 acc4 = make_float4(0.f, 0.f, 0.f, 0.f);

    for (int base = beg; base < end; base += 64) {
        int cnt = end - base; if (cnt > 64) cnt = 64;
        int sidx = 0;
        float4 e4 = make_float4(-1e30f, -1e30f, -1e30f, -1e30f);
        if (lane < cnt) {
            sidx = col[base + lane];
            float4 av = *(const float4*)&asrc[sidx * 4];
            float ex = av.x + ad4.x, ey = av.y + ad4.y,
                  ez = av.z + ad4.z, ew = av.w + ad4.w;
            e4.x = (ex > 0.f) ? ex : NEG * ex;
            e4.y = (ey > 0.f) ? ey : NEG * ey;
            e4.z = (ez > 0.f) ? ez : NEG * ez;
            e4.w = (ew > 0.f) ? ew : NEG * ew;
        }
        scol[wave][lane] = sidx;
        float4 M4 = e4;
#pragma unroll
        for (int s = 1; s < 64; s <<= 1) {
            M4.x = fmaxf(M4.x, __shfl_xor(M4.x, s));
            M4.y = fmaxf(M4.y, __shfl_xor(M4.y, s));
            M4.z = fmaxf(M4.z, __shfl_xor(M4.z, s));
            M4.w = fmaxf(M4.w, __shfl_xor(M4.w, s));
        }
        if (base == beg) {
            m4 = M4;               // first chunk: no rescale (acc/s are zero)
        } else {
            float4 nm;
            nm.x = fmaxf(m4.x, M4.x); nm.y = fmaxf(m4.y, M4.y);
            nm.z = fmaxf(m4.z, M4.z); nm.w = fmaxf(m4.w, M4.w);
            float4 sc;
            sc.x = __expf(m4.x - nm.x); sc.y = __expf(m4.y - nm.y);
            sc.z = __expf(m4.z - nm.z); sc.w = __expf(m4.w - nm.w);
            s4.x *= sc.x; s4.y *= sc.y; s4.z *= sc.z; s4.w *= sc.w;
            float rs = selh(sc, whead);
            acc4.x *= rs; acc4.y *= rs; acc4.z *= rs; acc4.w *= rs;
            m4 = nm;
        }
        float4 w4;
        w4.x = (lane < cnt) ? __expf(e4.x - m4.x) : 0.f;
        w4.y = (lane < cnt) ? __expf(e4.y - m4.y) : 0.f;
        w4.z = (lane < cnt) ? __expf(e4.z - m4.z) : 0.f;
        w4.w = (lane < cnt) ? __expf(e4.w - m4.w) : 0.f;
        *(float4*)&sw[wave][lane * 4] = w4;
        float4 S4 = w4;
#pragma unroll
        for (int s = 1; s < 64; s <<= 1) {
            S4.x += __shfl_xor(S4.x, s);
            S4.y += __shfl_xor(S4.y, s);
            S4.z += __shfl_xor(S4.z, s);
            S4.w += __shfl_xor(S4.w, s);
        }
        s4.x += S4.x; s4.y += S4.y; s4.z += S4.z; s4.w += S4.w;
        // paired fp16 feature gather: edge p+hl, 8B/lane, 512B/wave-instr.
        // lanes >= cnt wrote sidx=0 & w4=0, so the pad edge is a no-op.
#pragma unroll 4
        for (int p = 0; p < cnt; p += 2) {
            int s = scol[wave][p + hl];
            float wgt = sw[wave][(p + hl) * 4 + whead];
            f16x4 hv = *(const f16x4*)&h[(size_t)s * F + wl * 4];
            acc4.x = fmaf(wgt, (float)hv[0], acc4.x);
            acc4.y = fmaf(wgt, (float)hv[1], acc4.y);
            acc4.z = fmaf(wgt, (float)hv[2], acc4.z);
            acc4.w = fmaf(wgt, (float)hv[3], acc4.w);
        }
    }

    // combine edge-halves: channel c lives on lane wl in both halves
    acc4.x += __shfl_xor(acc4.x, 32);
    acc4.y += __shfl_xor(acc4.y, 32);
    acc4.z += __shfl_xor(acc4.z, 32);
    acc4.w += __shfl_xor(acc4.w, 32);

    if (hl == 0) {
        float ssum = selh(s4, whead);
        float inv = 1.f / (ssum + 1e-16f);
        float4 bv = *(const float4*)&bias[wl * 4];
        float ox = fmaxf(fmaf(acc4.x, inv, bv.x), 0.f);
        float oy = fmaxf(fmaf(acc4.y, inv, bv.y), 0.f);
        float oz = fmaxf(fmaf(acc4.z, inv, bv.z), 0.f);
        float ow = fmaxf(fmaf(acc4.w, inv, bv.w), 0.f);
        if constexpr (sizeof(OutT) == 4) {
            *(float4*)&xout[(size_t)n * F + wl * 4] = make_float4(ox, oy, oz, ow);
        } else {
            f16x4 st = {(_Float16)ox, (_Float16)oy, (_Float16)oz, (_Float16)ow};
            *(f16x4*)&xout[(size_t)n * F + wl * 4] = st;
        }
    }
}

// ---------------- final linear 128 -> 32: register-blocked GEMM ----------------
// X is fp16 (layer-3 output): staging loads f16x8 (16B/lane) and converts to
// fp32 during the LDS transpose. Compute path unchanged.

#define FCB 128

__global__ __launch_bounds__(256) void k_fc(const _Float16* __restrict__ X,
                                            const float* __restrict__ Wf,
                                            const float* __restrict__ bf,
                                            float* __restrict__ out) {
    __shared__ float WsT[128 * 36];   // [k][o], staged once
    __shared__ float XsT[32 * 132];   // [k][n] per 32-k chunk
    int tid = threadIdx.x;
    int bm = blockIdx.x * FCB;

#pragma unroll
    for (int u = 0; u < 16; u++) {
        int idx = tid + 256 * u;          // 0..4095
        int o = idx >> 7, k = idx & 127;
        WsT[k * 36 + o] = Wf[idx];
    }

    int tx = tid & 7;      // outputs tx*4 .. tx*4+3
    int ty = tid >> 3;     // nodes ty*4 .. ty*4+3
    float acc[4][4];
#pragma unroll
    for (int i = 0; i < 4; i++)
#pragma unroll
        for (int j = 0; j < 4; j++) acc[i][j] = 0.f;

    for (int k0 = 0; k0 < 128; k0 += 32) {
        __syncthreads();
        // stage XsT: 128 nodes x 4 units of 8 fp16 ch = 512 units, 2/thread
#pragma unroll
        for (int u = 0; u < 2; u++) {
            int f8 = tid + 256 * u;       // 0..511
            int r = f8 >> 2, c8 = f8 & 3;
            int n = bm + r;
            f16x8 v = {0, 0, 0, 0, 0, 0, 0, 0};
            if (n < N_NODES) v = *(const f16x8*)&X[(size_t)n * F + k0 + c8 * 8];
#pragma unroll
            for (int j = 0; j < 8; j++)
                XsT[(c8 * 8 + j) * 132 + r] = (float)v[j];
        }
        __syncthreads();

#pragma unroll
        for (int kk = 0; kk < 32; kk++) {
            float4 xv = *(float4*)&XsT[kk * 132 + ty * 4];
            float4 wv = *(float4*)&WsT[(k0 + kk) * 36 + tx * 4];
            float xs[4] = {xv.x, xv.y, xv.z, xv.w};
            float ws[4] = {wv.x, wv.y, wv.z, wv.w};
#pragma unroll
            for (int i = 0; i < 4; i++)
#pragma unroll
                for (int j = 0; j < 4; j++)
                    acc[i][j] = fmaf(xs[i], ws[j], acc[i][j]);
        }
    }

    float4 bv = *(const float4*)&bf[tx * 4];
#pragma unroll
    for (int i = 0; i < 4; i++) {
        int n = bm + ty * 4 + i;
        if (n < N_NODES) {
            float4 o4 = make_float4(acc[i][0] + bv.x, acc[i][1] + bv.y,
                                    acc[i][2] + bv.z, acc[i][3] + bv.w);
            *(float4*)&out[n * 32 + tx * 4] = o4;
        }
    }
}

// ---------------- launch ----------------

extern "C" void kernel_launch(void* const* d_in, const int* in_sizes, int n_in,
                              void* d_out, int out_size, void* d_ws, size_t ws_size,
                              hipStream_t stream) {
    const float* x      = (const float*)d_in[0];   // [N,128]
    const float* Ws     = (const float*)d_in[1];   // [3,128,128]
    const float* a_src  = (const float*)d_in[2];   // [3,4,32]
    const float* a_dst  = (const float*)d_in[3];   // [3,4,32]
    const float* cbias  = (const float*)d_in[4];   // [3,128]
    const float* Wf     = (const float*)d_in[5];   // [32,128]
    const float* bf     = (const float*)d_in[6];   // [32]
    const int*   ei     = (const int*)d_in[7];     // [2,800000]
    float* out = (float*)d_out;

    char* p = (char*)d_ws;
    auto carve = [&](size_t bytes) {
        char* r = p;
        p += (bytes + 255) & ~(size_t)255;
        return r;
    };
    float*    xA   = (float*)carve((size_t)N_NODES * F * 4);
    float*    xB   = (float*)carve((size_t)N_NODES * F * 4);
    _Float16* xC   = (_Float16*)carve((size_t)N_NODES * F * 2);  // layer-3 out
    _Float16* hbuf = (_Float16*)carve((size_t)N_NODES * F * 2);
    float* asrc = (float*)carve((size_t)N_NODES * NHEAD * 4);
    float* adst = (float*)carve((size_t)N_NODES * NHEAD * 4);
    int* deg    = (int*)carve((size_t)N_NODES * 4);
    int* rowptr = (int*)carve((size_t)(N_NODES + 1) * 4);
    int* rank   = (int*)carve((size_t)ETOT * 4);
    int* bsum   = (int*)carve((size_t)SCAN_B * 4);
    int* col    = (int*)carve((size_t)ETOT * 4);

    // ---- CSR build (dst-sorted adjacency), atomic-free fill ----
    k_zero<<<(N_NODES + 255) / 256, 256, 0, stream>>>(deg, N_NODES);
    k_deg<<<(ETOT + 255) / 256, 256, 0, stream>>>(ei, deg, rank);
    k_scan1<<<NBLK, SCAN_B, 0, stream>>>(deg, bsum);
    k_scan2<<<1, SCAN_B, 0, stream>>>(bsum);
    k_scan3<<<NBLK, SCAN_B, 0, stream>>>(deg, bsum, rowptr);
    k_fill<<<(ETOT + 255) / 256, 256, 0, stream>>>(ei, rowptr, rank, col);

    // ---- 3 GAT layers ----
    k_gemm<<<(N_NODES + GM - 1) / GM, 256, 0, stream>>>(
        x, Ws, a_src, a_dst, hbuf, asrc, adst);
    k_aggr<float><<<(N_NODES + 3) / 4, 256, 0, stream>>>(
        hbuf, asrc, adst, rowptr, col, cbias, xA);

    k_gemm<<<(N_NODES + GM - 1) / GM, 256, 0, stream>>>(
        xA, Ws + (size_t)F * F, a_src + F, a_dst + F, hbuf, asrc, adst);
    k_aggr<float><<<(N_NODES + 3) / 4, 256, 0, stream>>>(
        hbuf, asrc, adst, rowptr, col, cbias + F, xB);

    k_gemm<<<(N_NODES + GM - 1) / GM, 256, 0, stream>>>(
        xB, Ws + (size_t)2 * F * F, a_src + 2 * F, a_dst + 2 * F, hbuf, asrc, adst);
    k_aggr<_Float16><<<(N_NODES + 3) / 4, 256, 0, stream>>>(
        hbuf, asrc, adst, rowptr, col, cbias + 2 * F, xC);

    // ---- final linear (fp16 input) ----
    k_fc<<<(N_NODES + FCB - 1) / FCB, 256, 0, stream>>>(xC, Wf, bf, out);
}

// Round 10
// 323.950 us; speedup vs baseline: 3.7050x; 1.1408x over previous
//
#include <hip/hip_runtime.h>
#include <hip/hip_bf16.h>
#include <math.h>

#define N_NODES 50000
#define NE      800000
#define ETOT    (NE + N_NODES)   // edges + self loops = 850000
#define F       128              // F_in == H*C
#define NHEAD   4
#define NEG     0.2f

#define SCAN_B 256
#define NBLK   ((N_NODES + SCAN_B - 1) / SCAN_B)   // 196

typedef __attribute__((ext_vector_type(8))) short bf16x8;
typedef __attribute__((ext_vector_type(4))) float f32x4;
typedef _Float16 f16x8 __attribute__((ext_vector_type(8)));

// ---------------- CSR build (atomic-free fill via rank trick) ----------------

__global__ void k_zero(int* __restrict__ p, int n) {
    int i = blockIdx.x * blockDim.x + threadIdx.x;
    if (i < n) p[i] = 0;
}

__global__ void k_deg(const int* __restrict__ ei, int* __restrict__ deg,
                      int* __restrict__ rank) {
    int i = blockIdx.x * blockDim.x + threadIdx.x;
    if (i < ETOT) {
        int d = (i < NE) ? ei[NE + i] : (i - NE);
        rank[i] = atomicAdd(&deg[d], 1);
    }
}

__global__ void k_scan1(const int* __restrict__ deg, int* __restrict__ bsum) {
    __shared__ int sm[SCAN_B];
    int i = blockIdx.x * SCAN_B + threadIdx.x;
    sm[threadIdx.x] = (i < N_NODES) ? deg[i] : 0;
    __syncthreads();
    for (int s = SCAN_B / 2; s > 0; s >>= 1) {
        if (threadIdx.x < s) sm[threadIdx.x] += sm[threadIdx.x + s];
        __syncthreads();
    }
    if (threadIdx.x == 0) bsum[blockIdx.x] = sm[0];
}

__global__ void k_scan2(int* __restrict__ bsum) {
    __shared__ int sm[SCAN_B];
    int t = threadIdx.x;
    int v = (t < NBLK) ? bsum[t] : 0;
    sm[t] = v; __syncthreads();
    for (int s = 1; s < SCAN_B; s <<= 1) {
        int a = (t >= s) ? sm[t - s] : 0;
        __syncthreads();
        sm[t] += a;
        __syncthreads();
    }
    if (t < NBLK) bsum[t] = sm[t] - v;  // exclusive
}

__global__ void k_scan3(const int* __restrict__ deg, const int* __restrict__ bsum,
                        int* __restrict__ rowptr) {
    __shared__ int sm[SCAN_B];
    int t = threadIdx.x;
    int i = blockIdx.x * SCAN_B + t;
    int v = (i < N_NODES) ? deg[i] : 0;
    sm[t] = v; __syncthreads();
    for (int s = 1; s < SCAN_B; s <<= 1) {
        int a = (t >= s) ? sm[t - s] : 0;
        __syncthreads();
        sm[t] += a;
        __syncthreads();
    }
    int excl = sm[t] - v + bsum[blockIdx.x];
    if (i < N_NODES) rowptr[i] = excl;
    if (i == N_NODES - 1) rowptr[N_NODES] = excl + v;
}

__global__ void k_fill(const int* __restrict__ ei, const int* __restrict__ rowptr,
                       const int* __restrict__ rank, int* __restrict__ col) {
    int i = blockIdx.x * blockDim.x + threadIdx.x;
    if (i < ETOT) {
        int s, d;
        if (i < NE) { s = ei[i]; d = ei[NE + i]; }
        else        { s = i - NE; d = s; }
        col[rowptr[d] + rank[i]] = s;
    }
}

// ---------------- split helpers ----------------

__device__ __forceinline__ unsigned short f2bf(float x) {   // RNE truncate
    unsigned int u = __float_as_uint(x);
    u += 0x7FFFu + ((u >> 16) & 1u);
    return (unsigned short)(u >> 16);
}
__device__ __forceinline__ float bf2f(unsigned short h) {
    return __uint_as_float(((unsigned int)h) << 16);
}
__device__ __forceinline__ void cvt8(float4 a, float4 b, bf16x8* hi, bf16x8* lo) {
    float f[8] = {a.x, a.y, a.z, a.w, b.x, b.y, b.z, b.w};
    bf16x8 h, l;
#pragma unroll
    for (int j = 0; j < 8; j++) {
        unsigned short hu = f2bf(f[j]);
        h[j] = (short)hu;
        l[j] = (short)f2bf(f[j] - bf2f(hu));
    }
    *hi = h; *lo = l;
}
__device__ __forceinline__ void cvt8h(float4 a, float4 b, f16x8* hi, f16x8* lo) {
    float f[8] = {a.x, a.y, a.z, a.w, b.x, b.y, b.z, b.w};
    f16x8 h, l;
#pragma unroll
    for (int j = 0; j < 8; j++) {
        _Float16 hh = (_Float16)f[j];
        h[j] = hh;
        l[j] = (_Float16)(f[j] - (float)hh);
    }
    *hi = h; *lo = l;
}

__device__ __forceinline__ int lds_unit(int m, int q) {
    return 4 * m + (q ^ ((m >> 1) & 3));
}

#define GM 64

// ---------------- layer-1 GEMM: fp32 X, split-bf16, 3 MFMAs/tile ----------------

__global__ __launch_bounds__(256) void k_gemm(const float* __restrict__ X,
                                              const float* __restrict__ W,
                                              const float* __restrict__ a_s,
                                              const float* __restrict__ a_d,
                                              _Float16* __restrict__ hout,
                                              float* __restrict__ asrc,
                                              float* __restrict__ adst) {
    __shared__ short Ah[256 * 8], Al[256 * 8];
    __shared__ short Bh[512 * 8], Bl[512 * 8];
    int tid = threadIdx.x;
    int bm = blockIdx.x * GM;

    int am = tid >> 2, aq = tid & 3;
    int xunit = ((am >> 4) << 6) + lds_unit(am & 15, aq);
    int wj = tid >> 2, wq = tid & 3;
    int wunit = ((wj >> 4) << 6) + lds_unit(wj & 15, wq);

    int lane = tid & 63, wv = tid >> 6;
    int fm = lane & 15, fq = lane >> 4;
    int a_unit = (wv << 6) + lds_unit(fm, fq);
    int b_unit0 = lds_unit(fm, fq);

    f32x4 acc[8];
#pragma unroll
    for (int nt = 0; nt < 8; nt++) acc[nt] = (f32x4){0.f, 0.f, 0.f, 0.f};

    float4 xp0, xp1, wp0, wp1, wp2, wp3;
    int gr = bm + am;
    bool xok = (gr < N_NODES);
    const float* xrow = X + (size_t)gr * F + aq * 8;
    const float* wrow1 = W + (size_t)wj * F + wq * 8;
    const float* wrow2 = W + (size_t)(wj + 64) * F + wq * 8;
    float4 z4 = make_float4(0.f, 0.f, 0.f, 0.f);

    auto load_tile = [&](int k0) {
        xp0 = xok ? *(const float4*)(xrow + k0)     : z4;
        xp1 = xok ? *(const float4*)(xrow + k0 + 4) : z4;
        wp0 = *(const float4*)(wrow1 + k0);
        wp1 = *(const float4*)(wrow1 + k0 + 4);
        wp2 = *(const float4*)(wrow2 + k0);
        wp3 = *(const float4*)(wrow2 + k0 + 4);
    };
    auto store_tile = [&]() {
        bf16x8 hi, lo;
        cvt8(xp0, xp1, &hi, &lo);
        *(bf16x8*)&Ah[xunit * 8] = hi;  *(bf16x8*)&Al[xunit * 8] = lo;
        cvt8(wp0, wp1, &hi, &lo);
        *(bf16x8*)&Bh[wunit * 8] = hi;  *(bf16x8*)&Bl[wunit * 8] = lo;
        cvt8(wp2, wp3, &hi, &lo);
        *(bf16x8*)&Bh[(wunit + 256) * 8] = hi;  *(bf16x8*)&Bl[(wunit + 256) * 8] = lo;
    };

    load_tile(0);
    store_tile();
    __syncthreads();

#pragma unroll
    for (int t = 0; t < 4; t++) {
        if (t < 3) load_tile((t + 1) * 32);
        bf16x8 ah = *(bf16x8*)&Ah[a_unit * 8];
        bf16x8 al = *(bf16x8*)&Al[a_unit * 8];
#pragma unroll
        for (int nt = 0; nt < 8; nt++) {
            int bu = ((nt << 6) + b_unit0) * 8;
            bf16x8 bh = *(bf16x8*)&Bh[bu];
            bf16x8 bl = *(bf16x8*)&Bl[bu];
            acc[nt] = __builtin_amdgcn_mfma_f32_16x16x32_bf16(ah, bh, acc[nt], 0, 0, 0);
            acc[nt] = __builtin_amdgcn_mfma_f32_16x16x32_bf16(ah, bl, acc[nt], 0, 0, 0);
            acc[nt] = __builtin_amdgcn_mfma_f32_16x16x32_bf16(al, bh, acc[nt], 0, 0, 0);
        }
        __syncthreads();
        if (t < 3) { store_tile(); __syncthreads(); }
    }

    float as_v[8], ad_v[8];
#pragma unroll
    for (int nt = 0; nt < 8; nt++) {
        as_v[nt] = a_s[nt * 16 + fm];
        ad_v[nt] = a_d[nt * 16 + fm];
    }
#pragma unroll
    for (int r = 0; r < 4; r++) {
        int n = bm + wv * 16 + fq * 4 + r;
        bool ok = (n < N_NODES);
        if (ok) {
#pragma unroll
            for (int nt = 0; nt < 8; nt++)
                hout[(size_t)n * F + nt * 16 + fm] = (_Float16)acc[nt][r];
        }
        float ps[4], pd[4];
#pragma unroll
        for (int hh = 0; hh < 4; hh++) {
            ps[hh] = acc[2 * hh][r] * as_v[2 * hh] + acc[2 * hh + 1][r] * as_v[2 * hh + 1];
            pd[hh] = acc[2 * hh][r] * ad_v[2 * hh] + acc[2 * hh + 1][r] * ad_v[2 * hh + 1];
        }
#pragma unroll
        for (int s = 1; s < 16; s <<= 1) {
#pragma unroll
            for (int hh = 0; hh < 4; hh++) {
                ps[hh] += __shfl_xor(ps[hh], s);
                pd[hh] += __shfl_xor(pd[hh], s);
            }
        }
        if (ok && fm == 0) {
            *(float4*)&asrc[n * 4] = make_float4(ps[0], ps[1], ps[2], ps[3]);
            *(float4*)&adst[n * 4] = make_float4(pd[0], pd[1], pd[2], pd[3]);
        }
    }
}

// ---------------- layer-2/3 GEMM: fp16 X (exact f16 MFMA A), W split f16 hi/lo
// 2 MFMAs/tile; A staging is a raw 16B copy (no conversion). Same swizzle.

__global__ __launch_bounds__(256) void k_gemm16(const _Float16* __restrict__ X,
                                                const float* __restrict__ W,
                                                const float* __restrict__ a_s,
                                                const float* __restrict__ a_d,
                                                _Float16* __restrict__ hout,
                                                float* __restrict__ asrc,
                                                float* __restrict__ adst) {
    __shared__ _Float16 Ahf[256 * 8];                 // 4 KB
    __shared__ _Float16 Bhf[512 * 8], Blf[512 * 8];   // 8 KB each
    int tid = threadIdx.x;
    int bm = blockIdx.x * GM;

    int am = tid >> 2, aq = tid & 3;
    int xunit = ((am >> 4) << 6) + lds_unit(am & 15, aq);
    int wj = tid >> 2, wq = tid & 3;
    int wunit = ((wj >> 4) << 6) + lds_unit(wj & 15, wq);

    int lane = tid & 63, wv = tid >> 6;
    int fm = lane & 15, fq = lane >> 4;
    int a_unit = (wv << 6) + lds_unit(fm, fq);
    int b_unit0 = lds_unit(fm, fq);

    f32x4 acc[8];
#pragma unroll
    for (int nt = 0; nt < 8; nt++) acc[nt] = (f32x4){0.f, 0.f, 0.f, 0.f};

    f16x8 xp;
    float4 wp0, wp1, wp2, wp3;
    int gr = bm + am;
    bool xok = (gr < N_NODES);
    const _Float16* xrow = X + (size_t)gr * F + aq * 8;
    const float* wrow1 = W + (size_t)wj * F + wq * 8;
    const float* wrow2 = W + (size_t)(wj + 64) * F + wq * 8;

    auto load_tile = [&](int k0) {
        f16x8 zz = {0, 0, 0, 0, 0, 0, 0, 0};
        xp = xok ? *(const f16x8*)(xrow + k0) : zz;
        wp0 = *(const float4*)(wrow1 + k0);
        wp1 = *(const float4*)(wrow1 + k0 + 4);
        wp2 = *(const float4*)(wrow2 + k0);
        wp3 = *(const float4*)(wrow2 + k0 + 4);
    };
    auto store_tile = [&]() {
        *(f16x8*)&Ahf[xunit * 8] = xp;
        f16x8 hi, lo;
        cvt8h(wp0, wp1, &hi, &lo);
        *(f16x8*)&Bhf[wunit * 8] = hi;  *(f16x8*)&Blf[wunit * 8] = lo;
        cvt8h(wp2, wp3, &hi, &lo);
        *(f16x8*)&Bhf[(wunit + 256) * 8] = hi;  *(f16x8*)&Blf[(wunit + 256) * 8] = lo;
    };

    load_tile(0);
    store_tile();
    __syncthreads();

#pragma unroll
    for (int t = 0; t < 4; t++) {
        if (t < 3) load_tile((t + 1) * 32);
        f16x8 ah = *(f16x8*)&Ahf[a_unit * 8];
#pragma unroll
        for (int nt = 0; nt < 8; nt++) {
            int bu = ((nt << 6) + b_unit0) * 8;
            f16x8 bh = *(f16x8*)&Bhf[bu];
            f16x8 bl = *(f16x8*)&Blf[bu];
            acc[nt] = __builtin_amdgcn_mfma_f32_16x16x32_f16(ah, bh, acc[nt], 0, 0, 0);
            acc[nt] = __builtin_amdgcn_mfma_f32_16x16x32_f16(ah, bl, acc[nt], 0, 0, 0);
        }
        __syncthreads();
        if (t < 3) { store_tile(); __syncthreads(); }
    }

    float as_v[8], ad_v[8];
#pragma unroll
    for (int nt = 0; nt < 8; nt++) {
        as_v[nt] = a_s[nt * 16 + fm];
        ad_v[nt] = a_d[nt * 16 + fm];
    }
#pragma unroll
    for (int r = 0; r < 4; r++) {
        int n = bm + wv * 16 + fq * 4 + r;
        bool ok = (n < N_NODES);
        if (ok) {
#pragma unroll
            for (int nt = 0; nt < 8; nt++)
                hout[(size_t)n * F + nt * 16 + fm] = (_Float16)acc[nt][r];
        }
        float ps[4], pd[4];
#pragma unroll
        for (int hh = 0; hh < 4; hh++) {
            ps[hh] = acc[2 * hh][r] * as_v[2 * hh] + acc[2 * hh + 1][r] * as_v[2 * hh + 1];
            pd[hh] = acc[2 * hh][r] * ad_v[2 * hh] + acc[2 * hh + 1][r] * ad_v[2 * hh + 1];
        }
#pragma unroll
        for (int s = 1; s < 16; s <<= 1) {
#pragma unroll
            for (int hh = 0; hh < 4; hh++) {
                ps[hh] += __shfl_xor(ps[hh], s);
                pd[hh] += __shfl_xor(pd[hh], s);
            }
        }
        if (ok && fm == 0) {
            *(float4*)&asrc[n * 4] = make_float4(ps[0], ps[1], ps[2], ps[3]);
            *(float4*)&adst[n * 4] = make_float4(pd[0], pd[1], pd[2], pd[3]);
        }
    }
}

// ---------------- fused softmax + aggregate v4 ----------------
// No-max softmax: e = leaky(asrc+adst) is range-bounded (leaky damps negatives
// x0.2; positives << 88), so w = exp(e) cannot overflow/underflow harmfully and
// the max-butterfly + online-rescale disappear. Sum reduced TRANSPOSED: each
// lane exps its edge's 4 heads into swT[head][edge] (stride 68 -> conflict-
// free), lane-group g then b128-reads 4 edges of head g + 4-step butterfly.
// Gather: 4 edges/instr, 16 lanes x f16x8 (16B) per row; weight reads hit 16
// distinct banks (broadcast x4), conflict-free. One wave per node.

#define EPAD 68

__global__ __launch_bounds__(256) void k_aggr(const _Float16* __restrict__ h,
                                              const float* __restrict__ asrc,
                                              const float* __restrict__ adst,
                                              const int* __restrict__ rowptr,
                                              const int* __restrict__ col,
                                              const float* __restrict__ bias,
                                              _Float16* __restrict__ xout) {
    __shared__ int   scol[4][64];
    __shared__ float swT[4][4 * EPAD];
    int wave = threadIdx.x >> 6;
    int lane = threadIdx.x & 63;
    int n = blockIdx.x * 4 + wave;
    if (n >= N_NODES) return;
    int wl = lane & 15;        // channel-octet: channels wl*8 .. wl*8+7
    int he = lane >> 4;        // gather: edge sub-index; reduce: head id
    int hc = wl >> 2;          // head of this lane's channels
    int beg = rowptr[n], end = rowptr[n + 1];
    float4 ad4 = *(const float4*)&adst[n * 4];

    float s_run = 0.f;         // softmax denominator for head 'he'
    float acc[8];
#pragma unroll
    for (int j = 0; j < 8; j++) acc[j] = 0.f;

    for (int base = beg; base < end; base += 64) {
        int cnt = end - base; if (cnt > 64) cnt = 64;
        int sidx = 0;
        float4 w4 = make_float4(0.f, 0.f, 0.f, 0.f);
        if (lane < cnt) {
            sidx = col[base + lane];
            float4 av = *(const float4*)&asrc[sidx * 4];
            float ex = av.x + ad4.x, ey = av.y + ad4.y,
                  ez = av.z + ad4.z, ew = av.w + ad4.w;
            ex = (ex > 0.f) ? ex : NEG * ex;
            ey = (ey > 0.f) ? ey : NEG * ey;
            ez = (ez > 0.f) ? ez : NEG * ez;
            ew = (ew > 0.f) ? ew : NEG * ew;
            w4.x = __expf(ex); w4.y = __expf(ey);
            w4.z = __expf(ez); w4.w = __expf(ew);
        }
        scol[wave][lane] = sidx;
        swT[wave][0 * EPAD + lane] = w4.x;
        swT[wave][1 * EPAD + lane] = w4.y;
        swT[wave][2 * EPAD + lane] = w4.z;
        swT[wave][3 * EPAD + lane] = w4.w;
        __builtin_amdgcn_sched_barrier(0);   // pin LDS write->read order (same-wave, in-order DS)
        // sum for head 'he': 4 edges per lane, then 16-lane butterfly
        float4 wv4 = *(float4*)&swT[wave][he * EPAD + wl * 4];
        float S = (wv4.x + wv4.y) + (wv4.z + wv4.w);
#pragma unroll
        for (int s = 1; s < 16; s <<= 1) S += __shfl_xor(S, s);
        s_run += S;
        __builtin_amdgcn_sched_barrier(0);
        // gather: 4 edges per iteration (pad edges have w=0, sidx=0)
#pragma unroll 2
        for (int p = 0; p < cnt; p += 4) {
            int ep = p + he;
            int s = scol[wave][ep];
            float wgt = swT[wave][hc * EPAD + ep];
            f16x8 hv = *(const f16x8*)&h[(size_t)s * F + wl * 8];
#pragma unroll
            for (int j = 0; j < 8; j++)
                acc[j] = fmaf(wgt, (float)hv[j], acc[j]);
        }
        __builtin_amdgcn_sched_barrier(0);   // gather reads before next chunk's writes
    }

    // combine the 4 edge-subsets (he = bits 4..5)
#pragma unroll
    for (int j = 0; j < 8; j++) {
        acc[j] += __shfl_xor(acc[j], 16);
        acc[j] += __shfl_xor(acc[j], 32);
    }
    float sv = __shfl(s_run, hc * 16);       // denominator of this lane's head
    float inv = 1.f / (sv + 1e-16f);
    float4 b0 = *(const float4*)&bias[wl * 8];
    float4 b1 = *(const float4*)&bias[wl * 8 + 4];
    float bb[8] = {b0.x, b0.y, b0.z, b0.w, b1.x, b1.y, b1.z, b1.w};
    if (he == 0) {
        f16x8 st;
#pragma unroll
        for (int j = 0; j < 8; j++)
            st[j] = (_Float16)fmaxf(fmaf(acc[j], inv, bb[j]), 0.f);
        *(f16x8*)&xout[(size_t)n * F + wl * 8] = st;
    }
}

// ---------------- final linear 128 -> 32: register-blocked GEMM (fp16 X) ------

#define FCB 128

__global__ __launch_bounds__(256) void k_fc(const _Float16* __restrict__ X,
                                            const float* __restrict__ Wf,
                                            const float* __restrict__ bf,
                                            float* __restrict__ out) {
    __shared__ float WsT[128 * 36];   // [k][o], staged once
    __shared__ float XsT[32 * 132];   // [k][n] per 32-k chunk
    int tid = threadIdx.x;
    int bm = blockIdx.x * FCB;

#pragma unroll
    for (int u = 0; u < 16; u++) {
        int idx = tid + 256 * u;          // 0..4095
        int o = idx >> 7, k = idx & 127;
        WsT[k * 36 + o] = Wf[idx];
    }

    int tx = tid & 7;      // outputs tx*4 .. tx*4+3
    int ty = tid >> 3;     // nodes ty*4 .. ty*4+3
    float acc[4][4];
#pragma unroll
    for (int i = 0; i < 4; i++)
#pragma unroll
        for (int j = 0; j < 4; j++) acc[i][j] = 0.f;

    for (int k0 = 0; k0 < 128; k0 += 32) {
        __syncthreads();
#pragma unroll
        for (int u = 0; u < 2; u++) {
            int f8 = tid + 256 * u;       // 0..511
            int r = f8 >> 2, c8 = f8 & 3;
            int n = bm + r;
            f16x8 v = {0, 0, 0, 0, 0, 0, 0, 0};
            if (n < N_NODES) v = *(const f16x8*)&X[(size_t)n * F + k0 + c8 * 8];
#pragma unroll
            for (int j = 0; j < 8; j++)
                XsT[(c8 * 8 + j) * 132 + r] = (float)v[j];
        }
        __syncthreads();

#pragma unroll
        for (int kk = 0; kk < 32; kk++) {
            float4 xv = *(float4*)&XsT[kk * 132 + ty * 4];
            float4 wv = *(float4*)&WsT[(k0 + kk) * 36 + tx * 4];
            float xs[4] = {xv.x, xv.y, xv.z, xv.w};
            float ws[4] = {wv.x, wv.y, wv.z, wv.w};
#pragma unroll
            for (int i = 0; i < 4; i++)
#pragma unroll
                for (int j = 0; j < 4; j++)
                    acc[i][j] = fmaf(xs[i], ws[j], acc[i][j]);
        }
    }

    float4 bv = *(const float4*)&bf[tx * 4];
#pragma unroll
    for (int i = 0; i < 4; i++) {
        int n = bm + ty * 4 + i;
        if (n < N_NODES) {
            float4 o4 = make_float4(acc[i][0] + bv.x, acc[i][1] + bv.y,
                                    acc[i][2] + bv.z, acc[i][3] + bv.w);
            *(float4*)&out[n * 32 + tx * 4] = o4;
        }
    }
}

// ---------------- launch ----------------

extern "C" void kernel_launch(void* const* d_in, const int* in_sizes, int n_in,
                              void* d_out, int out_size, void* d_ws, size_t ws_size,
                              hipStream_t stream) {
    const float* x      = (const float*)d_in[0];   // [N,128]
    const float* Ws     = (const float*)d_in[1];   // [3,128,128]
    const float* a_src  = (const float*)d_in[2];   // [3,4,32]
    const float* a_dst  = (const float*)d_in[3];   // [3,4,32]
    const float* cbias  = (const float*)d_in[4];   // [3,128]
    const float* Wf     = (const float*)d_in[5];   // [32,128]
    const float* bf     = (const float*)d_in[6];   // [32]
    const int*   ei     = (const int*)d_in[7];     // [2,800000]
    float* out = (float*)d_out;

    char* p = (char*)d_ws;
    auto carve = [&](size_t bytes) {
        char* r = p;
        p += (bytes + 255) & ~(size_t)255;
        return r;
    };
    _Float16* xA   = (_Float16*)carve((size_t)N_NODES * F * 2);
    _Float16* xB   = (_Float16*)carve((size_t)N_NODES * F * 2);
    _Float16* xC   = (_Float16*)carve((size_t)N_NODES * F * 2);
    _Float16* hbuf = (_Float16*)carve((size_t)N_NODES * F * 2);
    float* asrc = (float*)carve((size_t)N_NODES * NHEAD * 4);
    float* adst = (float*)carve((size_t)N_NODES * NHEAD * 4);
    int* deg    = (int*)carve((size_t)N_NODES * 4);
    int* rowptr = (int*)carve((size_t)(N_NODES + 1) * 4);
    int* rank   = (int*)carve((size_t)ETOT * 4);
    int* bsum   = (int*)carve((size_t)SCAN_B * 4);
    int* col    = (int*)carve((size_t)ETOT * 4);

    // ---- CSR build (dst-sorted adjacency), atomic-free fill ----
    k_zero<<<(N_NODES + 255) / 256, 256, 0, stream>>>(deg, N_NODES);
    k_deg<<<(ETOT + 255) / 256, 256, 0, stream>>>(ei, deg, rank);
    k_scan1<<<NBLK, SCAN_B, 0, stream>>>(deg, bsum);
    k_scan2<<<1, SCAN_B, 0, stream>>>(bsum);
    k_scan3<<<NBLK, SCAN_B, 0, stream>>>(deg, bsum, rowptr);
    k_fill<<<(ETOT + 255) / 256, 256, 0, stream>>>(ei, rowptr, rank, col);

    int gaggr = (N_NODES + 3) / 4;
    int ggemm = (N_NODES + GM - 1) / GM;

    // ---- 3 GAT layers ----
    k_gemm<<<ggemm, 256, 0, stream>>>(x, Ws, a_src, a_dst, hbuf, asrc, adst);
    k_aggr<<<gaggr, 256, 0, stream>>>(hbuf, asrc, adst, rowptr, col, cbias, xA);

    k_gemm16<<<ggemm, 256, 0, stream>>>(xA, Ws + (size_t)F * F, a_src + F, a_dst + F,
                                        hbuf, asrc, adst);
    k_aggr<<<gaggr, 256, 0, stream>>>(hbuf, asrc, adst, rowptr, col, cbias + F, xB);

    k_gemm16<<<ggemm, 256, 0, stream>>>(xB, Ws + (size_t)2 * F * F, a_src + 2 * F,
                                        a_dst + 2 * F, hbuf, asrc, adst);
    k_aggr<<<gaggr, 256, 0, stream>>>(hbuf, asrc, adst, rowptr, col, cbias + 2 * F, xC);

    // ---- final linear (fp16 input) ----
    k_fc<<<(N_NODES + FCB - 1) / FCB, 256, 0, stream>>>(xC, Wf, bf, out);
}

// Round 11
// 323.938 us; speedup vs baseline: 3.7052x; 1.0000x over previous
//
#include <hip/hip_runtime.h>
#include <hip/hip_bf16.h>
#include <math.h>

#define N_NODES 50000
#define NE      800000
#define ETOT    (NE + N_NODES)   // edges + self loops = 850000
#define F       128              // F_in == H*C
#define NHEAD   4
#define NEG     0.2f

#define SCAN_B 256
#define NBLK   ((N_NODES + SCAN_B - 1) / SCAN_B)   // 196

typedef __attribute__((ext_vector_type(8))) short bf16x8;
typedef __attribute__((ext_vector_type(4))) float f32x4;
typedef _Float16 f16x8 __attribute__((ext_vector_type(8)));

// ---------------- CSR build (atomic-free fill via rank trick) ----------------

__global__ void k_deg(const int* __restrict__ ei, int* __restrict__ deg,
                      int* __restrict__ rank) {
    int i = blockIdx.x * blockDim.x + threadIdx.x;
    if (i < ETOT) {
        int d = (i < NE) ? ei[NE + i] : (i - NE);
        rank[i] = atomicAdd(&deg[d], 1);
    }
}

__global__ void k_scan1(const int* __restrict__ deg, int* __restrict__ bsum) {
    __shared__ int sm[SCAN_B];
    int i = blockIdx.x * SCAN_B + threadIdx.x;
    sm[threadIdx.x] = (i < N_NODES) ? deg[i] : 0;
    __syncthreads();
    for (int s = SCAN_B / 2; s > 0; s >>= 1) {
        if (threadIdx.x < s) sm[threadIdx.x] += sm[threadIdx.x + s];
        __syncthreads();
    }
    if (threadIdx.x == 0) bsum[blockIdx.x] = sm[0];
}

__global__ void k_scan2(int* __restrict__ bsum) {
    __shared__ int sm[SCAN_B];
    int t = threadIdx.x;
    int v = (t < NBLK) ? bsum[t] : 0;
    sm[t] = v; __syncthreads();
    for (int s = 1; s < SCAN_B; s <<= 1) {
        int a = (t >= s) ? sm[t - s] : 0;
        __syncthreads();
        sm[t] += a;
        __syncthreads();
    }
    if (t < NBLK) bsum[t] = sm[t] - v;  // exclusive
}

__global__ void k_scan3(const int* __restrict__ deg, const int* __restrict__ bsum,
                        int* __restrict__ rowptr) {
    __shared__ int sm[SCAN_B];
    int t = threadIdx.x;
    int i = blockIdx.x * SCAN_B + t;
    int v = (i < N_NODES) ? deg[i] : 0;
    sm[t] = v; __syncthreads();
    for (int s = 1; s < SCAN_B; s <<= 1) {
        int a = (t >= s) ? sm[t - s] : 0;
        __syncthreads();
        sm[t] += a;
        __syncthreads();
    }
    int excl = sm[t] - v + bsum[blockIdx.x];
    if (i < N_NODES) rowptr[i] = excl;
    if (i == N_NODES - 1) rowptr[N_NODES] = excl + v;
}

__global__ void k_fill(const int* __restrict__ ei, const int* __restrict__ rowptr,
                       const int* __restrict__ rank, int* __restrict__ col) {
    int i = blockIdx.x * blockDim.x + threadIdx.x;
    if (i < ETOT) {
        int s, d;
        if (i < NE) { s = ei[i]; d = ei[NE + i]; }
        else        { s = i - NE; d = s; }
        col[rowptr[d] + rank[i]] = s;
    }
}

// ---------------- split helpers ----------------

__device__ __forceinline__ unsigned short f2bf(float x) {   // RNE truncate
    unsigned int u = __float_as_uint(x);
    u += 0x7FFFu + ((u >> 16) & 1u);
    return (unsigned short)(u >> 16);
}
__device__ __forceinline__ float bf2f(unsigned short h) {
    return __uint_as_float(((unsigned int)h) << 16);
}
__device__ __forceinline__ void cvt8(float4 a, float4 b, bf16x8* hi, bf16x8* lo) {
    float f[8] = {a.x, a.y, a.z, a.w, b.x, b.y, b.z, b.w};
    bf16x8 h, l;
#pragma unroll
    for (int j = 0; j < 8; j++) {
        unsigned short hu = f2bf(f[j]);
        h[j] = (short)hu;
        l[j] = (short)f2bf(f[j] - bf2f(hu));
    }
    *hi = h; *lo = l;
}
__device__ __forceinline__ void cvt8h(float4 a, float4 b, f16x8* hi, f16x8* lo) {
    float f[8] = {a.x, a.y, a.z, a.w, b.x, b.y, b.z, b.w};
    f16x8 h, l;
#pragma unroll
    for (int j = 0; j < 8; j++) {
        _Float16 hh = (_Float16)f[j];
        h[j] = hh;
        l[j] = (_Float16)(f[j] - (float)hh);
    }
    *hi = h; *lo = l;
}

__device__ __forceinline__ int lds_unit(int m, int q) {
    return 4 * m + (q ^ ((m >> 1) & 3));
}

#define GM 64

// ---------------- layer-1 GEMM: fp32 X, split-bf16, 3 MFMAs/tile ----------------

__global__ __launch_bounds__(256) void k_gemm(const float* __restrict__ X,
                                              const float* __restrict__ W,
                                              const float* __restrict__ a_s,
                                              const float* __restrict__ a_d,
                                              _Float16* __restrict__ hout,
                                              float* __restrict__ asrc,
                                              float* __restrict__ adst) {
    __shared__ short Ah[256 * 8], Al[256 * 8];
    __shared__ short Bh[512 * 8], Bl[512 * 8];
    int tid = threadIdx.x;
    int bm = blockIdx.x * GM;

    int am = tid >> 2, aq = tid & 3;
    int xunit = ((am >> 4) << 6) + lds_unit(am & 15, aq);
    int wj = tid >> 2, wq = tid & 3;
    int wunit = ((wj >> 4) << 6) + lds_unit(wj & 15, wq);

    int lane = tid & 63, wv = tid >> 6;
    int fm = lane & 15, fq = lane >> 4;
    int a_unit = (wv << 6) + lds_unit(fm, fq);
    int b_unit0 = lds_unit(fm, fq);

    f32x4 acc[8];
#pragma unroll
    for (int nt = 0; nt < 8; nt++) acc[nt] = (f32x4){0.f, 0.f, 0.f, 0.f};

    float4 xp0, xp1, wp0, wp1, wp2, wp3;
    int gr = bm + am;
    bool xok = (gr < N_NODES);
    const float* xrow = X + (size_t)gr * F + aq * 8;
    const float* wrow1 = W + (size_t)wj * F + wq * 8;
    const float* wrow2 = W + (size_t)(wj + 64) * F + wq * 8;
    float4 z4 = make_float4(0.f, 0.f, 0.f, 0.f);

    auto load_tile = [&](int k0) {
        xp0 = xok ? *(const float4*)(xrow + k0)     : z4;
        xp1 = xok ? *(const float4*)(xrow + k0 + 4) : z4;
        wp0 = *(const float4*)(wrow1 + k0);
        wp1 = *(const float4*)(wrow1 + k0 + 4);
        wp2 = *(const float4*)(wrow2 + k0);
        wp3 = *(const float4*)(wrow2 + k0 + 4);
    };
    auto store_tile = [&]() {
        bf16x8 hi, lo;
        cvt8(xp0, xp1, &hi, &lo);
        *(bf16x8*)&Ah[xunit * 8] = hi;  *(bf16x8*)&Al[xunit * 8] = lo;
        cvt8(wp0, wp1, &hi, &lo);
        *(bf16x8*)&Bh[wunit * 8] = hi;  *(bf16x8*)&Bl[wunit * 8] = lo;
        cvt8(wp2, wp3, &hi, &lo);
        *(bf16x8*)&Bh[(wunit + 256) * 8] = hi;  *(bf16x8*)&Bl[(wunit + 256) * 8] = lo;
    };

    load_tile(0);
    store_tile();
    __syncthreads();

#pragma unroll
    for (int t = 0; t < 4; t++) {
        if (t < 3) load_tile((t + 1) * 32);
        bf16x8 ah = *(bf16x8*)&Ah[a_unit * 8];
        bf16x8 al = *(bf16x8*)&Al[a_unit * 8];
#pragma unroll
        for (int nt = 0; nt < 8; nt++) {
            int bu = ((nt << 6) + b_unit0) * 8;
            bf16x8 bh = *(bf16x8*)&Bh[bu];
            bf16x8 bl = *(bf16x8*)&Bl[bu];
            acc[nt] = __builtin_amdgcn_mfma_f32_16x16x32_bf16(ah, bh, acc[nt], 0, 0, 0);
            acc[nt] = __builtin_amdgcn_mfma_f32_16x16x32_bf16(ah, bl, acc[nt], 0, 0, 0);
            acc[nt] = __builtin_amdgcn_mfma_f32_16x16x32_bf16(al, bh, acc[nt], 0, 0, 0);
        }
        __syncthreads();
        if (t < 3) { store_tile(); __syncthreads(); }
    }

    float as_v[8], ad_v[8];
#pragma unroll
    for (int nt = 0; nt < 8; nt++) {
        as_v[nt] = a_s[nt * 16 + fm];
        ad_v[nt] = a_d[nt * 16 + fm];
    }
#pragma unroll
    for (int r = 0; r < 4; r++) {
        int n = bm + wv * 16 + fq * 4 + r;
        bool ok = (n < N_NODES);
        if (ok) {
#pragma unroll
            for (int nt = 0; nt < 8; nt++)
                hout[(size_t)n * F + nt * 16 + fm] = (_Float16)acc[nt][r];
        }
        float ps[4], pd[4];
#pragma unroll
        for (int hh = 0; hh < 4; hh++) {
            ps[hh] = acc[2 * hh][r] * as_v[2 * hh] + acc[2 * hh + 1][r] * as_v[2 * hh + 1];
            pd[hh] = acc[2 * hh][r] * ad_v[2 * hh] + acc[2 * hh + 1][r] * ad_v[2 * hh + 1];
        }
#pragma unroll
        for (int s = 1; s < 16; s <<= 1) {
#pragma unroll
            for (int hh = 0; hh < 4; hh++) {
                ps[hh] += __shfl_xor(ps[hh], s);
                pd[hh] += __shfl_xor(pd[hh], s);
            }
        }
        if (ok && fm == 0) {
            *(float4*)&asrc[n * 4] = make_float4(ps[0], ps[1], ps[2], ps[3]);
            *(float4*)&adst[n * 4] = make_float4(pd[0], pd[1], pd[2], pd[3]);
        }
    }
}

// ---------------- layer-2/3 GEMM: fp16 X (exact f16 MFMA A), W split f16 hi/lo

__global__ __launch_bounds__(256) void k_gemm16(const _Float16* __restrict__ X,
                                                const float* __restrict__ W,
                                                const float* __restrict__ a_s,
                                                const float* __restrict__ a_d,
                                                _Float16* __restrict__ hout,
                                                float* __restrict__ asrc,
                                                float* __restrict__ adst) {
    __shared__ _Float16 Ahf[256 * 8];                 // 4 KB
    __shared__ _Float16 Bhf[512 * 8], Blf[512 * 8];   // 8 KB each
    int tid = threadIdx.x;
    int bm = blockIdx.x * GM;

    int am = tid >> 2, aq = tid & 3;
    int xunit = ((am >> 4) << 6) + lds_unit(am & 15, aq);
    int wj = tid >> 2, wq = tid & 3;
    int wunit = ((wj >> 4) << 6) + lds_unit(wj & 15, wq);

    int lane = tid & 63, wv = tid >> 6;
    int fm = lane & 15, fq = lane >> 4;
    int a_unit = (wv << 6) + lds_unit(fm, fq);
    int b_unit0 = lds_unit(fm, fq);

    f32x4 acc[8];
#pragma unroll
    for (int nt = 0; nt < 8; nt++) acc[nt] = (f32x4){0.f, 0.f, 0.f, 0.f};

    f16x8 xp;
    float4 wp0, wp1, wp2, wp3;
    int gr = bm + am;
    bool xok = (gr < N_NODES);
    const _Float16* xrow = X + (size_t)gr * F + aq * 8;
    const float* wrow1 = W + (size_t)wj * F + wq * 8;
    const float* wrow2 = W + (size_t)(wj + 64) * F + wq * 8;

    auto load_tile = [&](int k0) {
        f16x8 zz = {0, 0, 0, 0, 0, 0, 0, 0};
        xp = xok ? *(const f16x8*)(xrow + k0) : zz;
        wp0 = *(const float4*)(wrow1 + k0);
        wp1 = *(const float4*)(wrow1 + k0 + 4);
        wp2 = *(const float4*)(wrow2 + k0);
        wp3 = *(const float4*)(wrow2 + k0 + 4);
    };
    auto store_tile = [&]() {
        *(f16x8*)&Ahf[xunit * 8] = xp;
        f16x8 hi, lo;
        cvt8h(wp0, wp1, &hi, &lo);
        *(f16x8*)&Bhf[wunit * 8] = hi;  *(f16x8*)&Blf[wunit * 8] = lo;
        cvt8h(wp2, wp3, &hi, &lo);
        *(f16x8*)&Bhf[(wunit + 256) * 8] = hi;  *(f16x8*)&Blf[(wunit + 256) * 8] = lo;
    };

    load_tile(0);
    store_tile();
    __syncthreads();

#pragma unroll
    for (int t = 0; t < 4; t++) {
        if (t < 3) load_tile((t + 1) * 32);
        f16x8 ah = *(f16x8*)&Ahf[a_unit * 8];
#pragma unroll
        for (int nt = 0; nt < 8; nt++) {
            int bu = ((nt << 6) + b_unit0) * 8;
            f16x8 bh = *(f16x8*)&Bhf[bu];
            f16x8 bl = *(f16x8*)&Blf[bu];
            acc[nt] = __builtin_amdgcn_mfma_f32_16x16x32_f16(ah, bh, acc[nt], 0, 0, 0);
            acc[nt] = __builtin_amdgcn_mfma_f32_16x16x32_f16(ah, bl, acc[nt], 0, 0, 0);
        }
        __syncthreads();
        if (t < 3) { store_tile(); __syncthreads(); }
    }

    float as_v[8], ad_v[8];
#pragma unroll
    for (int nt = 0; nt < 8; nt++) {
        as_v[nt] = a_s[nt * 16 + fm];
        ad_v[nt] = a_d[nt * 16 + fm];
    }
#pragma unroll
    for (int r = 0; r < 4; r++) {
        int n = bm + wv * 16 + fq * 4 + r;
        bool ok = (n < N_NODES);
        if (ok) {
#pragma unroll
            for (int nt = 0; nt < 8; nt++)
                hout[(size_t)n * F + nt * 16 + fm] = (_Float16)acc[nt][r];
        }
        float ps[4], pd[4];
#pragma unroll
        for (int hh = 0; hh < 4; hh++) {
            ps[hh] = acc[2 * hh][r] * as_v[2 * hh] + acc[2 * hh + 1][r] * as_v[2 * hh + 1];
            pd[hh] = acc[2 * hh][r] * ad_v[2 * hh] + acc[2 * hh + 1][r] * ad_v[2 * hh + 1];
        }
#pragma unroll
        for (int s = 1; s < 16; s <<= 1) {
#pragma unroll
            for (int hh = 0; hh < 4; hh++) {
                ps[hh] += __shfl_xor(ps[hh], s);
                pd[hh] += __shfl_xor(pd[hh], s);
            }
        }
        if (ok && fm == 0) {
            *(float4*)&asrc[n * 4] = make_float4(ps[0], ps[1], ps[2], ps[3]);
            *(float4*)&adst[n * 4] = make_float4(pd[0], pd[1], pd[2], pd[3]);
        }
    }
}

// ---------------- fused softmax + aggregate v4 (no-max softmax) ----------------

#define EPAD 68

__global__ __launch_bounds__(256) void k_aggr(const _Float16* __restrict__ h,
                                              const float* __restrict__ asrc,
                                              const float* __restrict__ adst,
                                              const int* __restrict__ rowptr,
                                              const int* __restrict__ col,
                                              const float* __restrict__ bias,
                                              _Float16* __restrict__ xout) {
    __shared__ int   scol[4][64];
    __shared__ float swT[4][4 * EPAD];
    int wave = threadIdx.x >> 6;
    int lane = threadIdx.x & 63;
    int n = blockIdx.x * 4 + wave;
    if (n >= N_NODES) return;
    int wl = lane & 15;        // channel-octet: channels wl*8 .. wl*8+7
    int he = lane >> 4;        // gather: edge sub-index; reduce: head id
    int hc = wl >> 2;          // head of this lane's channels
    int beg = rowptr[n], end = rowptr[n + 1];
    float4 ad4 = *(const float4*)&adst[n * 4];

    float s_run = 0.f;         // softmax denominator for head 'he'
    float acc[8];
#pragma unroll
    for (int j = 0; j < 8; j++) acc[j] = 0.f;

    for (int base = beg; base < end; base += 64) {
        int cnt = end - base; if (cnt > 64) cnt = 64;
        int sidx = 0;
        float4 w4 = make_float4(0.f, 0.f, 0.f, 0.f);
        if (lane < cnt) {
            sidx = col[base + lane];
            float4 av = *(const float4*)&asrc[sidx * 4];
            float ex = av.x + ad4.x, ey = av.y + ad4.y,
                  ez = av.z + ad4.z, ew = av.w + ad4.w;
            ex = (ex > 0.f) ? ex : NEG * ex;
            ey = (ey > 0.f) ? ey : NEG * ey;
            ez = (ez > 0.f) ? ez : NEG * ez;
            ew = (ew > 0.f) ? ew : NEG * ew;
            w4.x = __expf(ex); w4.y = __expf(ey);
            w4.z = __expf(ez); w4.w = __expf(ew);
        }
        scol[wave][lane] = sidx;
        swT[wave][0 * EPAD + lane] = w4.x;
        swT[wave][1 * EPAD + lane] = w4.y;
        swT[wave][2 * EPAD + lane] = w4.z;
        swT[wave][3 * EPAD + lane] = w4.w;
        __builtin_amdgcn_sched_barrier(0);   // pin LDS write->read order
        float4 wv4 = *(float4*)&swT[wave][he * EPAD + wl * 4];
        float S = (wv4.x + wv4.y) + (wv4.z + wv4.w);
#pragma unroll
        for (int s = 1; s < 16; s <<= 1) S += __shfl_xor(S, s);
        s_run += S;
        __builtin_amdgcn_sched_barrier(0);
#pragma unroll 2
        for (int p = 0; p < cnt; p += 4) {
            int ep = p + he;
            int s = scol[wave][ep];
            float wgt = swT[wave][hc * EPAD + ep];
            f16x8 hv = *(const f16x8*)&h[(size_t)s * F + wl * 8];
#pragma unroll
            for (int j = 0; j < 8; j++)
                acc[j] = fmaf(wgt, (float)hv[j], acc[j]);
        }
        __builtin_amdgcn_sched_barrier(0);   // gather reads before next chunk's writes
    }

#pragma unroll
    for (int j = 0; j < 8; j++) {
        acc[j] += __shfl_xor(acc[j], 16);
        acc[j] += __shfl_xor(acc[j], 32);
    }
    float sv = __shfl(s_run, hc * 16);
    float inv = 1.f / (sv + 1e-16f);
    float4 b0 = *(const float4*)&bias[wl * 8];
    float4 b1 = *(const float4*)&bias[wl * 8 + 4];
    float bb[8] = {b0.x, b0.y, b0.z, b0.w, b1.x, b1.y, b1.z, b1.w};
    if (he == 0) {
        f16x8 st;
#pragma unroll
        for (int j = 0; j < 8; j++)
            st[j] = (_Float16)fmaxf(fmaf(acc[j], inv, bb[j]), 0.f);
        *(f16x8*)&xout[(size_t)n * F + wl * 8] = st;
    }
}

// ---------------- final linear 128 -> 32: register-blocked GEMM (fp16 X) ------
// Round-11 conflict fix (round-10 PMC: 750720 SQ_LDS_BANK_CONFLICT):
//  - XsT staging: one wave writes 64 NODES x 16B (banks (4j+n)%32, n spans 64
//    -> 2-way, free) instead of 16 nodes x 64B (16 banks, 4-way). The global
//    read becomes a 256B-strided gather; each 64B line is L1-reused 4x.
//  - WsT staging: o-minor mapping -> banks (4k+o)%32 conflict-free; the
//    strided Wf read is 16KB L2-resident.

#define FCB 128

__global__ __launch_bounds__(256) void k_fc(const _Float16* __restrict__ X,
                                            const float* __restrict__ Wf,
                                            const float* __restrict__ bf,
                                            float* __restrict__ out) {
    __shared__ float WsT[128 * 36];   // [k][o], staged once
    __shared__ float XsT[32 * 132];   // [k][n] per 32-k chunk
    int tid = threadIdx.x;
    int bm = blockIdx.x * FCB;

#pragma unroll
    for (int u = 0; u < 16; u++) {
        int idx = tid + 256 * u;          // 0..4095
        int o = idx & 31, k = idx >> 5;   // o-minor: conflict-free LDS writes
        WsT[k * 36 + o] = Wf[o * 128 + k];
    }

    int tx = tid & 7;      // outputs tx*4 .. tx*4+3
    int ty = tid >> 3;     // nodes ty*4 .. ty*4+3
    float acc[4][4];
#pragma unroll
    for (int i = 0; i < 4; i++)
#pragma unroll
        for (int j = 0; j < 4; j++) acc[i][j] = 0.f;

    for (int k0 = 0; k0 < 128; k0 += 32) {
        __syncthreads();
        // stage XsT[k][n]: idx -> (n = idx&127, c = idx>>7); wave spans 64 n
#pragma unroll
        for (int u = 0; u < 2; u++) {
            int idx = tid + 256 * u;      // 0..511
            int nn = idx & 127, c = idx >> 7;
            int gn = bm + nn;
            f16x8 v = {0, 0, 0, 0, 0, 0, 0, 0};
            if (gn < N_NODES) v = *(const f16x8*)&X[(size_t)gn * F + k0 + c * 8];
#pragma unroll
            for (int j = 0; j < 8; j++)
                XsT[(c * 8 + j) * 132 + nn] = (float)v[j];
        }
        __syncthreads();

#pragma unroll
        for (int kk = 0; kk < 32; kk++) {
            float4 xv = *(float4*)&XsT[kk * 132 + ty * 4];
            float4 wv = *(float4*)&WsT[(k0 + kk) * 36 + tx * 4];
            float xs[4] = {xv.x, xv.y, xv.z, xv.w};
            float ws[4] = {wv.x, wv.y, wv.z, wv.w};
#pragma unroll
            for (int i = 0; i < 4; i++)
#pragma unroll
                for (int j = 0; j < 4; j++)
                    acc[i][j] = fmaf(xs[i], ws[j], acc[i][j]);
        }
    }

    float4 bv = *(const float4*)&bf[tx * 4];
#pragma unroll
    for (int i = 0; i < 4; i++) {
        int n = bm + ty * 4 + i;
        if (n < N_NODES) {
            float4 o4 = make_float4(acc[i][0] + bv.x, acc[i][1] + bv.y,
                                    acc[i][2] + bv.z, acc[i][3] + bv.w);
            *(float4*)&out[n * 32 + tx * 4] = o4;
        }
    }
}

// ---------------- launch ----------------

extern "C" void kernel_launch(void* const* d_in, const int* in_sizes, int n_in,
                              void* d_out, int out_size, void* d_ws, size_t ws_size,
                              hipStream_t stream) {
    const float* x      = (const float*)d_in[0];   // [N,128]
    const float* Ws     = (const float*)d_in[1];   // [3,128,128]
    const float* a_src  = (const float*)d_in[2];   // [3,4,32]
    const float* a_dst  = (const float*)d_in[3];   // [3,4,32]
    const float* cbias  = (const float*)d_in[4];   // [3,128]
    const float* Wf     = (const float*)d_in[5];   // [32,128]
    const float* bf     = (const float*)d_in[6];   // [32]
    const int*   ei     = (const int*)d_in[7];     // [2,800000]
    float* out = (float*)d_out;

    char* p = (char*)d_ws;
    auto carve = [&](size_t bytes) {
        char* r = p;
        p += (bytes + 255) & ~(size_t)255;
        return r;
    };
    _Float16* xA   = (_Float16*)carve((size_t)N_NODES * F * 2);
    _Float16* xB   = (_Float16*)carve((size_t)N_NODES * F * 2);
    _Float16* xC   = (_Float16*)carve((size_t)N_NODES * F * 2);
    _Float16* hbuf = (_Float16*)carve((size_t)N_NODES * F * 2);
    float* asrc = (float*)carve((size_t)N_NODES * NHEAD * 4);
    float* adst = (float*)carve((size_t)N_NODES * NHEAD * 4);
    int* deg    = (int*)carve((size_t)N_NODES * 4);
    int* rowptr = (int*)carve((size_t)(N_NODES + 1) * 4);
    int* rank   = (int*)carve((size_t)ETOT * 4);
    int* bsum   = (int*)carve((size_t)SCAN_B * 4);
    int* col    = (int*)carve((size_t)ETOT * 4);

    // ---- CSR build (dst-sorted adjacency), atomic-free fill ----
    hipMemsetAsync(deg, 0, (size_t)N_NODES * 4, stream);   // replaces k_zero
    k_deg<<<(ETOT + 255) / 256, 256, 0, stream>>>(ei, deg, rank);
    k_scan1<<<NBLK, SCAN_B, 0, stream>>>(deg, bsum);
    k_scan2<<<1, SCAN_B, 0, stream>>>(bsum);
    k_scan3<<<NBLK, SCAN_B, 0, stream>>>(deg, bsum, rowptr);
    k_fill<<<(ETOT + 255) / 256, 256, 0, stream>>>(ei, rowptr, rank, col);

    int gaggr = (N_NODES + 3) / 4;
    int ggemm = (N_NODES + GM - 1) / GM;

    // ---- 3 GAT layers ----
    k_gemm<<<ggemm, 256, 0, stream>>>(x, Ws, a_src, a_dst, hbuf, asrc, adst);
    k_aggr<<<gaggr, 256, 0, stream>>>(hbuf, asrc, adst, rowptr, col, cbias, xA);

    k_gemm16<<<ggemm, 256, 0, stream>>>(xA, Ws + (size_t)F * F, a_src + F, a_dst + F,
                                        hbuf, asrc, adst);
    k_aggr<<<gaggr, 256, 0, stream>>>(hbuf, asrc, adst, rowptr, col, cbias + F, xB);

    k_gemm16<<<ggemm, 256, 0, stream>>>(xB, Ws + (size_t)2 * F * F, a_src + 2 * F,
                                        a_dst + 2 * F, hbuf, asrc, adst);
    k_aggr<<<gaggr, 256, 0, stream>>>(hbuf, asrc, adst, rowptr, col, cbias + 2 * F, xC);

    // ---- final linear (fp16 input) ----
    k_fc<<<(N_NODES + FCB - 1) / FCB, 256, 0, stream>>>(xC, Wf, bf, out);
}